// Round 5
// baseline (2861.801 us; speedup 1.0000x reference)
//
#include <hip/hip_runtime.h>
#include <math.h>

#define Bc 2
#define Sc 2048
#define Dc 1024
#define Hc 16
#define HDc 64
#define FPOLY 4160
#define MHID 2048
#define FFNH 2730
#define FFNHP 2752   // FFNH padded to mult of 32 (K pad, zero-filled)
#define GGH 64
#define NTOK 4096
#define NACT 128
#define MCH 2048     // memory-forward M chunk

typedef __bf16 bf16;
typedef __attribute__((ext_vector_type(8))) __bf16 bf16x8;
typedef __attribute__((ext_vector_type(4))) float f32x4;

#define AS1 __attribute__((address_space(1)))
#define AS3 __attribute__((address_space(3)))

__device__ __forceinline__ void gload16(const void* g, void* l) {
    __builtin_amdgcn_global_load_lds((AS1 const void*)g, (AS3 void*)l, 16, 0, 0);
}

// ---------------------------------------------------------------- bf16 MFMA GEMM (LDS, big tiles)
// C = act(alpha*[sptr]*A@Bt^T + beta*Cin).  A:(M,K) bf16 row-major, Bt:(N,K) bf16.
// K%32==0, M%128==0. N arbitrary; Bt rows allocated to ceil(N/128)*128.
template<int OUTBF, int CINBF>
__global__ __launch_bounds__(256) void gemm_bt(
    const bf16* __restrict__ A, const bf16* __restrict__ Bt,
    const void* __restrict__ Cin, void* __restrict__ Cout,
    int M, int N, int K, int ldc,
    float alpha, float beta, int act, const float* __restrict__ sptr)
{
    __shared__ bf16 As[128 * 32];
    __shared__ bf16 Bs[128 * 32];
    const int tid = threadIdx.x;
    const int w = tid >> 6, lane = tid & 63;
    const int bm = blockIdx.y * 128, bn = blockIdx.x * 128;
    const int wm = (w >> 1) * 64, wn = (w & 1) * 64;
    f32x4 acc[4][4];
#pragma unroll
    for (int i = 0; i < 4; ++i)
#pragma unroll
        for (int j = 0; j < 4; ++j) { acc[i][j][0] = 0.f; acc[i][j][1] = 0.f; acc[i][j][2] = 0.f; acc[i][j][3] = 0.f; }
    const int idx0 = tid, idx1 = tid + 256;
    const int r0 = idx0 >> 2, r1 = idx1 >> 2;
    const int g0 = ((idx0 & 3) ^ ((r0 >> 1) & 3)) * 8;
    const int g1 = ((idx1 & 3) ^ ((r1 >> 1) & 3)) * 8;
    char* ldsA0 = (char*)As + w * 1024;
    char* ldsB0 = (char*)Bs + w * 1024;
    const int lrow = lane & 15;
    const int q = lane >> 4;
    int aoff[4], boff[4];
#pragma unroll
    for (int t = 0; t < 4; ++t) {
        int ar = wm + t * 16 + lrow;
        aoff[t] = ar * 32 + ((q ^ ((ar >> 1) & 3)) * 8);
        int br = wn + t * 16 + lrow;
        boff[t] = br * 32 + ((q ^ ((br >> 1) & 3)) * 8);
    }
    const bf16* Arow0 = A + (size_t)(bm + r0) * K + g0;
    const bf16* Arow1 = A + (size_t)(bm + r1) * K + g1;
    const bf16* Brow0 = Bt + (size_t)(bn + r0) * K + g0;
    const bf16* Brow1 = Bt + (size_t)(bn + r1) * K + g1;
    for (int k0 = 0; k0 < K; k0 += 32) {
        gload16(Arow0 + k0, ldsA0);
        gload16(Arow1 + k0, ldsA0 + 4096);
        gload16(Brow0 + k0, ldsB0);
        gload16(Brow1 + k0, ldsB0 + 4096);
        __syncthreads();
        bf16x8 af[4], bfr[4];
#pragma unroll
        for (int t = 0; t < 4; ++t) af[t] = *(const bf16x8*)&As[aoff[t]];
#pragma unroll
        for (int t = 0; t < 4; ++t) bfr[t] = *(const bf16x8*)&Bs[boff[t]];
#pragma unroll
        for (int mt = 0; mt < 4; ++mt)
#pragma unroll
            for (int nt = 0; nt < 4; ++nt)
                acc[mt][nt] = __builtin_amdgcn_mfma_f32_16x16x32_bf16(af[mt], bfr[nt], acc[mt][nt], 0, 0, 0);
        __syncthreads();
    }
    const float amul = alpha * (sptr ? *sptr : 1.f);
#pragma unroll
    for (int nt = 0; nt < 4; ++nt) {
        const int col = bn + wn + nt * 16 + lrow;
        if (col >= N) continue;
#pragma unroll
        for (int mt = 0; mt < 4; ++mt) {
            const int rbase = bm + wm + mt * 16 + q * 4;
#pragma unroll
            for (int r = 0; r < 4; ++r) {
                const size_t o = (size_t)(rbase + r) * ldc + col;
                float v = amul * acc[mt][nt][r];
                if (beta != 0.f)
                    v += beta * (CINBF ? (float)((const bf16*)Cin)[o] : ((const float*)Cin)[o]);
                if (act == 1) v = v / (1.f + __expf(-v));
                if (OUTBF) ((bf16*)Cout)[o] = (bf16)v;
                else       ((float*)Cout)[o] = v;
            }
        }
    }
}

// ---------------------------------------------------------------- barrier-free direct MFMA GEMM
// For skinny / latency-bound shapes. Fragments straight from global, no LDS, no barriers.
// Block = 128 rows (4 waves x 32) x 128 cols. Rows of A (and Bt) beyond M (N) must be
// ALLOCATED readable; stores are row/col masked. K%64==0 preferred (unroll 2), K%32 required.
template<int OUTBF, int CINBF>
__global__ __launch_bounds__(256) void gemm_direct(
    const bf16* __restrict__ A, const bf16* __restrict__ Bt,
    const void* __restrict__ Cin, void* __restrict__ Cout,
    int M, int N, int K, int ldc,
    float alpha, float beta, int act, const float* __restrict__ sptr)
{
    const int tid = threadIdx.x, w = tid >> 6, lane = tid & 63;
    const int lrow = lane & 15, quad = lane >> 4;
    const int bm = blockIdx.y * 128 + w * 32;
    const int bn = blockIdx.x * 128;
    f32x4 acc[2][8];
#pragma unroll
    for (int mt = 0; mt < 2; ++mt)
#pragma unroll
        for (int nt = 0; nt < 8; ++nt) { acc[mt][nt][0] = 0.f; acc[mt][nt][1] = 0.f; acc[mt][nt][2] = 0.f; acc[mt][nt][3] = 0.f; }
    const bf16* Abase = A + (size_t)(bm + lrow) * K + quad * 8;
    const bf16* Bbase = Bt + (size_t)(bn + lrow) * K + quad * 8;
#pragma unroll 2
    for (int k0 = 0; k0 < K; k0 += 32) {
        bf16x8 af0 = *(const bf16x8*)(Abase + k0);
        bf16x8 af1 = *(const bf16x8*)(Abase + (size_t)16 * K + k0);
#pragma unroll
        for (int nt = 0; nt < 8; ++nt) {
            bf16x8 bfr = *(const bf16x8*)(Bbase + (size_t)nt * 16 * K + k0);
            acc[0][nt] = __builtin_amdgcn_mfma_f32_16x16x32_bf16(af0, bfr, acc[0][nt], 0, 0, 0);
            acc[1][nt] = __builtin_amdgcn_mfma_f32_16x16x32_bf16(af1, bfr, acc[1][nt], 0, 0, 0);
        }
    }
    const float amul = alpha * (sptr ? *sptr : 1.f);
#pragma unroll
    for (int nt = 0; nt < 8; ++nt) {
        const int col = bn + nt * 16 + lrow;
        if (col >= N) continue;
#pragma unroll
        for (int mt = 0; mt < 2; ++mt) {
            const int rbase = bm + mt * 16 + quad * 4;
#pragma unroll
            for (int r = 0; r < 4; ++r) {
                const int row = rbase + r;
                if (row >= M) continue;
                const size_t o = (size_t)row * ldc + col;
                float v = amul * acc[mt][nt][r];
                if (beta != 0.f)
                    v += beta * (CINBF ? (float)((const bf16*)Cin)[o] : ((const float*)Cin)[o]);
                if (act == 1) v = v / (1.f + __expf(-v));
                if (OUTBF) ((bf16*)Cout)[o] = (bf16)v;
                else       ((float*)Cout)[o] = v;
            }
        }
    }
}

// ---------------------------------------------------------------- batched 128x128x128 bf16 MFMA
// z=3 batches. C[z] = alpha*A[z]@Bt[z]^T + beta*Min[z] + dg*I ; optionally also C^T.
template<int DUALT>
__global__ __launch_bounds__(256) void bmm128(
    const bf16* __restrict__ Ab, const bf16* __restrict__ Btb,
    const bf16* __restrict__ Minb, bf16* __restrict__ Cb, bf16* __restrict__ CTb,
    float alpha, float beta, float dg)
{
    const int z = blockIdx.x;
    const bf16* A = Ab + (size_t)z * 16384;
    const bf16* Bt = Btb + (size_t)z * 16384;
    const int tid = threadIdx.x, w = tid >> 6, lane = tid & 63;
    const int lrow = lane & 15, quad = lane >> 4;
    const int bm = w * 32;
    f32x4 acc[2][8];
#pragma unroll
    for (int mt = 0; mt < 2; ++mt)
#pragma unroll
        for (int nt = 0; nt < 8; ++nt) { acc[mt][nt][0] = 0.f; acc[mt][nt][1] = 0.f; acc[mt][nt][2] = 0.f; acc[mt][nt][3] = 0.f; }
#pragma unroll
    for (int k0 = 0; k0 < 128; k0 += 32) {
        bf16x8 af0 = *(const bf16x8*)(A + (size_t)(bm + lrow) * 128 + k0 + quad * 8);
        bf16x8 af1 = *(const bf16x8*)(A + (size_t)(bm + 16 + lrow) * 128 + k0 + quad * 8);
#pragma unroll
        for (int nt = 0; nt < 8; ++nt) {
            bf16x8 bfr = *(const bf16x8*)(Bt + (size_t)(nt * 16 + lrow) * 128 + k0 + quad * 8);
            acc[0][nt] = __builtin_amdgcn_mfma_f32_16x16x32_bf16(af0, bfr, acc[0][nt], 0, 0, 0);
            acc[1][nt] = __builtin_amdgcn_mfma_f32_16x16x32_bf16(af1, bfr, acc[1][nt], 0, 0, 0);
        }
    }
#pragma unroll
    for (int nt = 0; nt < 8; ++nt) {
        const int col = nt * 16 + lrow;
#pragma unroll
        for (int mt = 0; mt < 2; ++mt) {
#pragma unroll
            for (int r = 0; r < 4; ++r) {
                const int row = bm + mt * 16 + quad * 4 + r;
                float v = alpha * acc[mt][nt][r];
                if (beta != 0.f) v += beta * (float)Minb[(size_t)z * 16384 + row * 128 + col];
                if (dg != 0.f && row == col) v += dg;
                Cb[(size_t)z * 16384 + row * 128 + col] = (bf16)v;
                if (DUALT) CTb[(size_t)z * 16384 + col * 128 + row] = (bf16)v;
            }
        }
    }
}

__global__ void copy3_kernel(const bf16* __restrict__ a, const bf16* __restrict__ b,
                             bf16* __restrict__ ca, bf16* __restrict__ cb)
{
    int i = blockIdx.x * 256 + threadIdx.x;   // grid 192 -> 49152
    ca[i] = a[i]; cb[i] = b[i];
}

// per-batch: n2 = <S[z],C[z]>; Cb=bf16(C/n2); Sb=bf16(S); invn[z] = 1/(sqrt(n2)+1e-7)
__global__ __launch_bounds__(256) void ns_norm_kernel(
    const float* __restrict__ S, const float* __restrict__ C,
    bf16* __restrict__ Sb, bf16* __restrict__ Cb, float* __restrict__ invn)
{
    const int z = blockIdx.x;
    const float* s = S + (size_t)z * 16384;
    const float* c = C + (size_t)z * 16384;
    float acc = 0.f;
    for (int i = threadIdx.x; i < 16384; i += 256) acc += s[i] * c[i];
    __shared__ float red[256];
    red[threadIdx.x] = acc; __syncthreads();
    for (int st = 128; st; st >>= 1) {
        if (threadIdx.x < st) red[threadIdx.x] += red[threadIdx.x + st];
        __syncthreads();
    }
    float inv = 1.f / (sqrtf(red[0]) + 1e-7f);
    float inv2 = inv * inv;
    for (int i = threadIdx.x; i < 16384; i += 256) {
        Cb[(size_t)z * 16384 + i] = (bf16)(c[i] * inv2);
        Sb[(size_t)z * 16384 + i] = (bf16)s[i];
    }
    if (threadIdx.x == 0) invn[z] = inv;
}

// ---------------------------------------------------------------- converts
__global__ __launch_bounds__(256) void tconv_kernel(
    const float* __restrict__ W, bf16* __restrict__ Wt, int K, int N, int Kpad)
{
    __shared__ float t[32][33];
    const int k0 = blockIdx.x * 32, n0 = blockIdx.y * 32;
    const int tx = threadIdx.x & 31, ty = threadIdx.x >> 5;
#pragma unroll
    for (int r = 0; r < 4; ++r) {
        int gk = k0 + ty + r * 8, gn = n0 + tx;
        t[ty + r * 8][tx] = (gk < K && gn < N) ? W[(size_t)gk * N + gn] : 0.f;
    }
    __syncthreads();
#pragma unroll
    for (int r = 0; r < 4; ++r) {
        int gn = n0 + ty + r * 8, gk = k0 + tx;
        if (gn < N && gk < Kpad) Wt[(size_t)gn * Kpad + gk] = (bf16)t[tx][ty + r * 8];
    }
}

__global__ void cvt_kernel(const float* __restrict__ in, bf16* __restrict__ out, int n)
{
    for (int i = blockIdx.x * 256 + threadIdx.x; i < n; i += gridDim.x * 256)
        out[i] = (bf16)in[i];
}

// vb (b,s,h,d) -> vt (b,h,d,s)
__global__ __launch_bounds__(256) void vtrans_kernel(
    const bf16* __restrict__ vb, bf16* __restrict__ vt)
{
    __shared__ bf16 t[32][33];
    const int s0 = blockIdx.x * 32, d0 = blockIdx.y * 32, bh = blockIdx.z;
    const int b = bh >> 4, h = bh & 15;
    const int tx = threadIdx.x & 31, ty = threadIdx.x >> 5;
#pragma unroll
    for (int r = 0; r < 4; ++r) {
        int s = s0 + ty + r * 8;
        t[ty + r * 8][tx] = vb[((size_t)b * Sc + s) * Dc + h * 64 + d0 + tx];
    }
    __syncthreads();
#pragma unroll
    for (int r = 0; r < 4; ++r) {
        int d = d0 + ty + r * 8;
        vt[((size_t)bh * 64 + d) * Sc + s0 + tx] = t[tx][ty + r * 8];
    }
}

// ---------------------------------------------------------------- small kernels
__global__ __launch_bounds__(256) void rms_rows(
    const float* __restrict__ in, const float* __restrict__ w,
    bf16* __restrict__ out, int D)
{
    const int row = blockIdx.x;
    const float* r = in + (size_t)row * D;
    bf16* o = out + (size_t)row * D;
    float s = 0.f;
    for (int i = threadIdx.x; i < D; i += 256) { float v = r[i]; s += v * v; }
    __shared__ float red[256];
    red[threadIdx.x] = s;
    __syncthreads();
    for (int st = 128; st; st >>= 1) {
        if (threadIdx.x < st) red[threadIdx.x] += red[threadIdx.x + st];
        __syncthreads();
    }
    float rs = rsqrtf(red[0] / (float)D + 1e-6f);
    for (int i = threadIdx.x; i < D; i += 256) o[i] = (bf16)(r[i] * rs * w[i]);
}

__global__ __launch_bounds__(256) void gamma_kernel(
    const float* __restrict__ gg1, const float* __restrict__ w2,
    float* __restrict__ gamma)
{
    const int tid = threadIdx.x, w = tid >> 6, lane = tid & 63;
    const int t = blockIdx.x * 4 + w;
    float v = gg1[(size_t)t * GGH + lane];
    v = v / (1.f + expf(-v));
    v *= w2[lane];
#pragma unroll
    for (int off = 32; off; off >>= 1) v += __shfl_xor(v, off);
    if (lane == 0) gamma[t] = 1.f / (1.f + expf(-v));
}

__global__ __launch_bounds__(256) void snr_one(
    const bf16* __restrict__ src, const float* __restrict__ w,
    bf16* __restrict__ dst)
{
    const int tid = threadIdx.x, wv = tid >> 6, lane = tid & 63;
    const int s = blockIdx.x * 4 + wv;
    const int h = blockIdx.y, b = blockIdx.z;
    const size_t row = ((size_t)b * Sc + s) * Dc + h * 64;
    float v = (float)src[row + lane];
    float ss = v * v;
#pragma unroll
    for (int off = 32; off; off >>= 1) ss += __shfl_xor(ss, off);
    v = v * rsqrtf(ss / 64.f + 1e-6f) * w[lane];
    const int j = lane & 31;
    float inv = powf(10000.f, -(float)j / 32.f);
    float ang = (float)s * inv;
    float sn = sinf(ang), cs = cosf(ang);
    float p = __shfl_xor(v, 32);
    float o;
    if (lane < 32) o = v * cs - p * sn;
    else           o = p * sn + v * cs;
    const size_t od = (((size_t)b * Hc + h) * Sc + s) * 64 + lane;
    dst[od] = (bf16)o;
}

__global__ void kpsum_kernel(const bf16* __restrict__ kn, float* __restrict__ psum)
{
    const int bh = blockIdx.x, c = blockIdx.y, d = threadIdx.x;
    const size_t base = (size_t)bh * Sc * 64 + (size_t)c * 128 * 64 + d;
    float s = 0.f;
    for (int i = 0; i < 128; ++i) s += (float)kn[base + (size_t)i * 64];
    psum[((size_t)bh * 16 + c) * 64 + d] = s;
}

__global__ void qmem2_kernel(
    const bf16* __restrict__ qn, const bf16* __restrict__ kn,
    const float* __restrict__ gamma, const float* __restrict__ psum,
    float* __restrict__ qmem)
{
    const int bh = blockIdx.x, c = blockIdx.y;
    const int b = bh >> 4, hh = bh & 15;
    const int d = threadIdx.x;
    const size_t base = (size_t)bh * Sc * 64;
    float run = 0.f;
    for (int cc = 0; cc < c; ++cc) run += psum[((size_t)bh * 16 + cc) * 64 + d];
    for (int s = c * 128; s < c * 128 + 128; ++s) {
        run += (float)kn[base + (size_t)s * 64 + d];
        float cm = run / (float)(s + 1);
        float g = gamma[b * Sc + s];
        float qv = (float)qn[base + (size_t)s * 64 + d];
        qmem[((size_t)(b * Sc + s)) * Dc + hh * 64 + d] = g * qv + (1.f - g) * cm;
    }
}

// ---------------------------------------------------------------- MFMA flash attention
__global__ __launch_bounds__(256) void attn_mfma(
    const bf16* __restrict__ qn, const bf16* __restrict__ kn,
    const bf16* __restrict__ vt, bf16* __restrict__ outp)
{
    const int qt = blockIdx.x;
    const int h = blockIdx.y, b = blockIdx.z;
    const int bh = b * Hc + h;
    const int tid = threadIdx.x, w = tid >> 6, lane = tid & 63;
    const int lrow = lane & 15, quad = lane >> 4;
    const int qb = qt * 128;
    const int wq = w * 32;
    __shared__ bf16 Ps[4][32][136];
    bf16x8 qf[2][2];
    const bf16* qbase = qn + ((size_t)bh * Sc + qb + wq) * 64;
#pragma unroll
    for (int mt = 0; mt < 2; ++mt)
#pragma unroll
        for (int ks = 0; ks < 2; ++ks)
            qf[mt][ks] = *(const bf16x8*)(qbase + (size_t)(mt * 16 + lrow) * 64 + ks * 32 + quad * 8);
    f32x4 oacc[2][4];
#pragma unroll
    for (int mt = 0; mt < 2; ++mt)
#pragma unroll
        for (int nt = 0; nt < 4; ++nt) { oacc[mt][nt][0] = 0.f; oacc[mt][nt][1] = 0.f; oacc[mt][nt][2] = 0.f; oacc[mt][nt][3] = 0.f; }
    float m_i[2][4], l_i[2][4];
#pragma unroll
    for (int mt = 0; mt < 2; ++mt)
#pragma unroll
        for (int r = 0; r < 4; ++r) { m_i[mt][r] = -1e30f; l_i[mt][r] = 0.f; }
    const bf16* kbase = kn + (size_t)bh * Sc * 64;
    const bf16* vtb = vt + (size_t)bh * 64 * Sc;
    for (int k0 = 0; k0 <= qb; k0 += 128) {
        f32x4 sacc[2][8];
#pragma unroll
        for (int mt = 0; mt < 2; ++mt)
#pragma unroll
            for (int nt = 0; nt < 8; ++nt) { sacc[mt][nt][0] = 0.f; sacc[mt][nt][1] = 0.f; sacc[mt][nt][2] = 0.f; sacc[mt][nt][3] = 0.f; }
#pragma unroll
        for (int ks = 0; ks < 2; ++ks) {
            bf16x8 kf[8];
#pragma unroll
            for (int nt = 0; nt < 8; ++nt)
                kf[nt] = *(const bf16x8*)(kbase + (size_t)(k0 + nt * 16 + lrow) * 64 + ks * 32 + quad * 8);
#pragma unroll
            for (int mt = 0; mt < 2; ++mt)
#pragma unroll
                for (int nt = 0; nt < 8; ++nt)
                    sacc[mt][nt] = __builtin_amdgcn_mfma_f32_16x16x32_bf16(qf[mt][ks], kf[nt], sacc[mt][nt], 0, 0, 0);
        }
        const bool diag = (k0 == qb);
#pragma unroll
        for (int mt = 0; mt < 2; ++mt) {
            float mx[4] = {-1e30f, -1e30f, -1e30f, -1e30f};
#pragma unroll
            for (int nt = 0; nt < 8; ++nt) {
                int kc = k0 + nt * 16 + lrow;
#pragma unroll
                for (int r = 0; r < 4; ++r) {
                    float v = sacc[mt][nt][r] * 0.125f;
                    if (diag && kc > qb + wq + mt * 16 + quad * 4 + r) v = -1e30f;
                    sacc[mt][nt][r] = v;
                    mx[r] = fmaxf(mx[r], v);
                }
            }
#pragma unroll
            for (int r = 0; r < 4; ++r) {
#pragma unroll
                for (int off = 1; off < 16; off <<= 1) mx[r] = fmaxf(mx[r], __shfl_xor(mx[r], off));
                float mnew = fmaxf(m_i[mt][r], mx[r]);
                float corr = __expf(m_i[mt][r] - mnew);
                m_i[mt][r] = mnew;
                l_i[mt][r] *= corr;
#pragma unroll
                for (int nt2 = 0; nt2 < 4; ++nt2) oacc[mt][nt2][r] *= corr;
            }
            float sum[4] = {0.f, 0.f, 0.f, 0.f};
#pragma unroll
            for (int nt = 0; nt < 8; ++nt)
#pragma unroll
                for (int r = 0; r < 4; ++r) {
                    float p = __expf(sacc[mt][nt][r] - m_i[mt][r]);
                    sacc[mt][nt][r] = p;
                    sum[r] += p;
                }
#pragma unroll
            for (int r = 0; r < 4; ++r) {
#pragma unroll
                for (int off = 1; off < 16; off <<= 1) sum[r] += __shfl_xor(sum[r], off);
                l_i[mt][r] += sum[r];
            }
#pragma unroll
            for (int nt = 0; nt < 8; ++nt)
#pragma unroll
                for (int r = 0; r < 4; ++r)
                    Ps[w][mt * 16 + quad * 4 + r][nt * 16 + lrow] = (bf16)sacc[mt][nt][r];
        }
#pragma unroll
        for (int ks = 0; ks < 4; ++ks) {
            bf16x8 pf[2];
#pragma unroll
            for (int mt = 0; mt < 2; ++mt)
                pf[mt] = *(const bf16x8*)&Ps[w][mt * 16 + lrow][ks * 32 + quad * 8];
#pragma unroll
            for (int nt = 0; nt < 4; ++nt) {
                bf16x8 vf = *(const bf16x8*)(vtb + (size_t)(nt * 16 + lrow) * Sc + k0 + ks * 32 + quad * 8);
#pragma unroll
                for (int mt = 0; mt < 2; ++mt)
                    oacc[mt][nt] = __builtin_amdgcn_mfma_f32_16x16x32_bf16(pf[mt], vf, oacc[mt][nt], 0, 0, 0);
            }
        }
    }
#pragma unroll
    for (int mt = 0; mt < 2; ++mt)
#pragma unroll
        for (int nt = 0; nt < 4; ++nt)
#pragma unroll
            for (int r = 0; r < 4; ++r) {
                int row = qb + wq + mt * 16 + quad * 4 + r;
                int dcol = nt * 16 + lrow;
                outp[((size_t)b * Sc + row) * Dc + h * 64 + dcol] = (bf16)(oacc[mt][nt][r] / l_i[mt][r]);
            }
}

__global__ __launch_bounds__(256) void gather_active(
    const float* __restrict__ qmem, const bf16* __restrict__ vbuf,
    float* __restrict__ xa, bf16* __restrict__ xab, float* __restrict__ va)
{
    const int t = blockIdx.x;
    const int b = t >> 6;
    const int s = Sc - 64 + (t & 63);
    const float* qrow = qmem + ((size_t)(b * Sc + s)) * Dc;
    const bf16* vrow = vbuf + ((size_t)(b * Sc + s)) * Dc;
    for (int i = threadIdx.x; i < Dc; i += 256) {
        float q = qrow[i];
        xa[(size_t)t * Dc + i] = q;
        xab[(size_t)t * Dc + i] = (bf16)q;
        va[(size_t)t * Dc + i] = (float)vrow[i];
    }
}

__global__ void wvec_kernel(const float* __restrict__ gamma,
                            float* __restrict__ wvec, float* __restrict__ wsum)
{
    const int t = threadIdx.x;
    const int b = t >> 6, si = t & 63;
    const int s = Sc - 64 + si;
    float v = gamma[b * Sc + s] * powf(0.95f, (float)(Sc - 1 - s));
    wvec[t] = v;
    __shared__ float red[128];
    red[t] = v; __syncthreads();
    for (int st = 64; st; st >>= 1) { if (t < st) red[t] += red[t + st]; __syncthreads(); }
    if (t == 0) wsum[0] = red[0];
}

__global__ __launch_bounds__(256) void phi2_f32(
    const float* __restrict__ z, float* __restrict__ feat, bf16* __restrict__ featb)
{
    const int f = blockIdx.x * 256 + threadIdx.x;
    const int t = blockIdx.y;
    if (f >= FPOLY) return;
    const float* zr = z + (size_t)t * 64;
    float v;
    if (f < 64) v = zr[f];
    else { int i = (f - 64) >> 6, j = (f - 64) & 63; v = zr[i] * zr[j] * 0.125f; }
    feat[(size_t)t * FPOLY + f] = v;
    featb[(size_t)t * FPOLY + f] = (bf16)v;
}

__global__ __launch_bounds__(256) void phi2_bf16(
    const float* __restrict__ z, bf16* __restrict__ feat)
{
    const int f = blockIdx.x * 256 + threadIdx.x;
    const int t = blockIdx.y;
    if (f >= FPOLY) return;
    const float* zr = z + (size_t)t * 64;
    float v;
    if (f < 64) v = zr[f];
    else { int i = (f - 64) >> 6, j = (f - 64) & 63; v = zr[i] * zr[j] * 0.125f; }
    feat[(size_t)t * FPOLY + f] = (bf16)v;
}

__global__ void silu_kernel(const float* __restrict__ in, float* __restrict__ out,
                            bf16* __restrict__ outb, int n)
{
    int i = blockIdx.x * 256 + threadIdx.x;
    if (i < n) {
        float v = in[i];
        float s = v / (1.f + expf(-v));
        out[i] = s; outb[i] = (bf16)s;
    }
}

__global__ void dpred_kernel(const float* __restrict__ pred, const float* __restrict__ va,
                             const float* __restrict__ wvec, const float* __restrict__ wsum,
                             float* __restrict__ dpred, bf16* __restrict__ dpredb)
{
    int i = blockIdx.x * 256 + threadIdx.x;
    if (i < NACT * Dc) {
        int t = i >> 10;
        float v = 2.f * wvec[t] / (wsum[0] + 1e-8f) * (pred[i] - va[i]);
        dpred[i] = v; dpredb[i] = (bf16)v;
    }
}

__global__ void dsilu_kernel(const float* __restrict__ dsu, const float* __restrict__ u,
                             float* __restrict__ du, bf16* __restrict__ dub, int n)
{
    int i = blockIdx.x * 256 + threadIdx.x;
    if (i < n) {
        float uv = u[i];
        float sg = 1.f / (1.f + expf(-uv));
        float v = dsu[i] * sg * (1.f + uv * (1.f - sg));
        du[i] = v; dub[i] = (bf16)v;
    }
}

__global__ void dz_kernel(const float* __restrict__ dfeat, const float* __restrict__ za,
                          float* __restrict__ dz, bf16* __restrict__ dzb)
{
    const int t = blockIdx.x;
    const int k = threadIdx.x;
    const float* df = dfeat + (size_t)t * FPOLY;
    const float* z = za + (size_t)t * 64;
    float s1 = 0.f, s2 = 0.f;
    for (int j = 0; j < 64; ++j) {
        float zj = z[j];
        s1 += df[64 + k * 64 + j] * zj;
        s2 += df[64 + j * 64 + k] * zj;
    }
    float v = df[k] + 0.125f * (s1 + s2);
    dz[(size_t)t * 64 + k] = v;
    dzb[(size_t)t * 64 + k] = (bf16)v;
}

__global__ void sgate_kernel(const float* __restrict__ mg, float* __restrict__ out)
{
    out[0] = 1.f / (1.f + expf(-mg[0]));
}

__global__ void mulpad_kernel(bf16* __restrict__ a, const bf16* __restrict__ b)
{
    int i = blockIdx.x * 256 + threadIdx.x;
    if (i >= NTOK * FFNHP) return;
    int k = i % FFNHP;
    if (k >= FFNH) { a[i] = (bf16)0.f; return; }
    a[i] = (bf16)((float)a[i] * (float)b[i]);
}

// ---------------------------------------------------------------- launch
extern "C" void kernel_launch(void* const* d_in, const int* in_sizes, int n_in,
                              void* d_out, int out_size, void* d_ws, size_t ws_size,
                              hipStream_t stream)
{
    const float* x     = (const float*)d_in[0];
    const float* n1w   = (const float*)d_in[1];
    const float* n2w   = (const float*)d_in[2];
    const float* qkvw  = (const float*)d_in[3];
    const float* qnw   = (const float*)d_in[4];
    const float* knw   = (const float*)d_in[5];
    const float* gw1   = (const float*)d_in[6];
    const float* gw2   = (const float*)d_in[7];
    const float* mwk   = (const float*)d_in[8];
    const float* mw1   = (const float*)d_in[9];
    const float* mw2   = (const float*)d_in[10];
    const float* mgate = (const float*)d_in[11];
    const float* wow   = (const float*)d_in[12];
    const float* fw1   = (const float*)d_in[13];
    const float* fw2   = (const float*)d_in[14];
    const float* fw3   = (const float*)d_in[15];
    float* outp = (float*)d_out;

    char* base = (char*)d_ws;
    size_t off = 0;
    auto takeB = [&](size_t bytes) { char* p = base + off; off += (bytes + 255) & ~(size_t)255; return p; };

    // slabs (liveness-overlaid)
    char* slabA  = takeB(22544384);  // vt (16.8M) -> featC (17.0M) -> ff1b (22.5M)
    char* slabBC = takeB(16777216);  // qnb+knb -> x2 fp32
    char* slabD  = takeB(8388608);   // vb -> t1b
    char* slabE  = takeB(22544384);  // qmem fp32 (16.8M) -> ff3b (22.5M)
    char* slabF  = takeB(8388608);   // qtb -> attnb -> qmemb
    char* slabG  = takeB(17301504);  // hb (8.4M) -> mw1b (17.3M, 4224 rows) -> h2b (8.4M)
    bf16* vt    = (bf16*)slabA;  bf16* featC = (bf16*)slabA;  bf16* ff1b = (bf16*)slabA;
    bf16* qnb = (bf16*)slabBC;   bf16* knb = (bf16*)(slabBC + 8388608);
    float* x2 = (float*)slabBC;
    bf16* vb = (bf16*)slabD;     bf16* t1b = (bf16*)slabD;
    float* qmem = (float*)slabE; bf16* ff3b = (bf16*)slabE;
    bf16* qtb = (bf16*)slabF;    bf16* attnb = (bf16*)slabF;  bf16* qmemb = (bf16*)slabF;
    bf16* hb = (bf16*)slabG;     bf16* mw1b = (bf16*)slabG;   bf16* h2b = (bf16*)slabG;

    // bf16 weights
    bf16* qkvwT = (bf16*)takeB(6291456);
    bf16* gw1T  = (bf16*)takeB(262144);    // 128 rows alloc / 64 real
    bf16* wowT  = (bf16*)takeB(2097152);
    bf16* mw1T  = (bf16*)takeB(17039360);
    bf16* mw2T  = (bf16*)takeB(4194304);
    bf16* fw1T  = (bf16*)takeB(5767168);
    bf16* fw3T  = (bf16*)takeB(5767168);
    bf16* fw2T  = (bf16*)takeB(5636096);
    bf16* mw2b  = (bf16*)takeB(4194304);   // straight copy (2048,1024)
    bf16* mwkTb = (bf16*)takeB(262144);    // (64 real/128 alloc, 1024)
    bf16* wkuTb = (bf16*)takeB(262144);    // (64 real/128 alloc, 1024)

    // fp32 misc
    float* zf    = (float*)takeB(1048576);
    float* gg1   = (float*)takeB(1048576);
    float* gamma = (float*)takeB(16384);
    float* wvec  = (float*)takeB(512);
    float* scal  = (float*)takeB(256);     // [0]=wsum [2]=sig(gate) [8..10]=invn
    float* psum  = (float*)takeB(131072);
    float* xa    = (float*)takeB(524288);
    float* va    = (float*)takeB(524288);
    float* za    = (float*)takeB(32768);
    float* featA = (float*)takeB(2129920);
    float* ua    = (float*)takeB(1048576);
    float* sua   = (float*)takeB(1048576);
    float* preda = (float*)takeB(524288);
    float* dpreda= (float*)takeB(524288);
    float* dsua  = (float*)takeB(1048576);
    float* dua   = (float*)takeB(1048576);
    float* dfeata= (float*)takeB(2129920);
    float* dza   = (float*)takeB(32768);
    float* SA    = (float*)takeB(196608);  // 3 x 128x128 fp32
    float* CA    = (float*)takeB(196608);
    // bf16 misc
    bf16* featAb = (bf16*)takeB(1064960);
    bf16* suab   = (bf16*)takeB(524288);
    bf16* xab    = (bf16*)takeB(262144);
    bf16* duab   = (bf16*)takeB(524288);
    bf16* dpredab= (bf16*)takeB(262144);
    bf16* dzab   = (bf16*)takeB(16384);
    bf16* PT1Tb  = (bf16*)takeB(524288);   // (2048,128)
    bf16* PT2Tb  = (bf16*)takeB(262144);   // (1024,128)
    bf16* PT3Tb  = (bf16*)takeB(32768);    // (64 real/128 alloc,128)
    bf16* tBb    = (bf16*)takeB(524288);
    bf16* duaTb  = (bf16*)takeB(524288);   // (2048,128)
    bf16* dpredaTb=(bf16*)takeB(262144);   // (1024,128)
    bf16* dzaTb  = (bf16*)takeB(32768);    // (64 real/128 alloc,128)
    bf16* xaTb   = (bf16*)takeB(262144);   // (1024,128)
    // NS bf16 (each 3x128x128)
    bf16* Sb16  = (bf16*)takeB(98304);
    bf16* Cb16  = (bf16*)takeB(98304);
    bf16* Mb16  = (bf16*)takeB(98304);
    bf16* MTb16 = (bf16*)takeB(98304);
    bf16* Fb16  = (bf16*)takeB(98304);
    bf16* FTb16 = (bf16*)takeB(98304);
    bf16* FcAb  = (bf16*)takeB(98304);
    bf16* FcTAb = (bf16*)takeB(98304);
    bf16* FcBb  = (bf16*)takeB(98304);
    bf16* FcTBb = (bf16*)takeB(98304);
    bf16* Zb16  = (bf16*)takeB(98304);
    bf16* ZTb16 = (bf16*)takeB(98304);

    auto gemmB = [&](int outbf, int cinbf, const bf16* A, const bf16* Bt,
                     const void* Cin, void* C, int M, int N, int K, int ldc,
                     float alpha, float beta, int act, const float* sptr) {
        dim3 grid((N + 127) / 128, M / 128);
        if (outbf && cinbf) gemm_bt<1, 1><<<grid, 256, 0, stream>>>(A, Bt, Cin, C, M, N, K, ldc, alpha, beta, act, sptr);
        else if (outbf)     gemm_bt<1, 0><<<grid, 256, 0, stream>>>(A, Bt, Cin, C, M, N, K, ldc, alpha, beta, act, sptr);
        else                gemm_bt<0, 0><<<grid, 256, 0, stream>>>(A, Bt, Cin, C, M, N, K, ldc, alpha, beta, act, sptr);
    };
    auto gdir = [&](int outbf, int cinbf, const bf16* A, const bf16* Bt,
                    const void* Cin, void* C, int M, int N, int K, int ldc,
                    float alpha, float beta, int act, const float* sptr) {
        dim3 grid((N + 127) / 128, (M + 127) / 128);
        if (outbf && cinbf)      gemm_direct<1, 1><<<grid, 256, 0, stream>>>(A, Bt, Cin, C, M, N, K, ldc, alpha, beta, act, sptr);
        else if (outbf)          gemm_direct<1, 0><<<grid, 256, 0, stream>>>(A, Bt, Cin, C, M, N, K, ldc, alpha, beta, act, sptr);
        else if (cinbf)          gemm_direct<0, 1><<<grid, 256, 0, stream>>>(A, Bt, Cin, C, M, N, K, ldc, alpha, beta, act, sptr);
        else                     gemm_direct<0, 0><<<grid, 256, 0, stream>>>(A, Bt, Cin, C, M, N, K, ldc, alpha, beta, act, sptr);
    };
    auto tconv = [&](const float* W, bf16* Wt, int K, int N, int Kpad) {
        tconv_kernel<<<dim3((Kpad + 31) / 32, (N + 31) / 32), 256, 0, stream>>>(W, Wt, K, N, Kpad);
    };

    // 0. weight converts
    tconv(qkvw, qkvwT, Dc, 3 * Dc, Dc);
    tconv(gw1, gw1T, Dc, GGH, Dc);
    tconv(wow, wowT, Dc, Dc, Dc);
    tconv(mw1, mw1T, FPOLY, MHID, FPOLY);
    tconv(mw2, mw2T, MHID, Dc, MHID);
    tconv(fw1, fw1T, Dc, FFNH, Dc);
    tconv(fw3, fw3T, Dc, FFNH, Dc);
    tconv(fw2, fw2T, FFNH, Dc, FFNHP);
    tconv(mwk, mwkTb, Dc, HDc, Dc);
    cvt_kernel<<<2048, 256, 0, stream>>>(mw2, mw2b, MHID * Dc);
    sgate_kernel<<<1, 1, 0, stream>>>(mgate, scal + 2);

    // 1-2. rmsnorm, q/k/v, gamma
    rms_rows<<<NTOK, 256, 0, stream>>>(x, n1w, hb, Dc);
    gemmB(1, 0, hb, qkvwT,          nullptr, qtb, NTOK, Dc, Dc, Dc, 1.f, 0.f, 0, nullptr);
    snr_one<<<dim3(Sc / 4, Hc, Bc), 256, 0, stream>>>(qtb, qnw, qnb);
    gemmB(1, 0, hb, qkvwT + (size_t)1024 * Dc, nullptr, qtb, NTOK, Dc, Dc, Dc, 1.f, 0.f, 0, nullptr);
    snr_one<<<dim3(Sc / 4, Hc, Bc), 256, 0, stream>>>(qtb, knw, knb);
    gemmB(1, 0, hb, qkvwT + (size_t)2048 * Dc, nullptr, vb, NTOK, Dc, Dc, Dc, 1.f, 0.f, 0, nullptr);
    gdir(0, 0, hb, gw1T, nullptr, gg1, NTOK, GGH, Dc, GGH, 1.f, 0.f, 0, nullptr);
    gamma_kernel<<<NTOK / 4, 256, 0, stream>>>(gg1, gw2, gamma);
    cvt_kernel<<<2048, 256, 0, stream>>>(mw1, mw1b, FPOLY * MHID);   // hb dead

    // 3. V transpose, q_mem, attention
    vtrans_kernel<<<dim3(Sc / 32, 2, Bc * Hc), 256, 0, stream>>>(vb, vt);
    kpsum_kernel<<<dim3(Bc * Hc, 16), 64, 0, stream>>>(knb, psum);
    qmem2_kernel<<<dim3(Bc * Hc, 16), 64, 0, stream>>>(qnb, knb, gamma, psum, qmem);
    attn_mfma<<<dim3(Sc / 128, Hc, Bc), 256, 0, stream>>>(qnb, knb, vt, attnb);

    // 4. actives
    gather_active<<<NACT, 256, 0, stream>>>(qmem, vb, xa, xab, va);
    wvec_kernel<<<1, 128, 0, stream>>>(gamma, wvec, scal);

    // 5. gradient chain (128 active tokens) -- all direct MFMA
    gdir(0, 0, xab, mwkTb, nullptr, za, NACT, HDc, Dc, HDc, 1.f, 0.f, 0, nullptr);
    phi2_f32<<<dim3((FPOLY + 255) / 256, NACT), 256, 0, stream>>>(za, featA, featAb);
    gdir(0, 0, featAb, mw1T, nullptr, ua, NACT, MHID, FPOLY, MHID, 1.f, 0.f, 0, nullptr);
    silu_kernel<<<(NACT * MHID + 255) / 256, 256, 0, stream>>>(ua, sua, suab, NACT * MHID);
    gdir(0, 0, suab, mw2T, nullptr, preda, NACT, Dc, MHID, Dc, 1.f, 0.f, 0, nullptr);
    dpred_kernel<<<(NACT * Dc + 255) / 256, 256, 0, stream>>>(preda, va, wvec, scal, dpreda, dpredab);
    gdir(0, 0, dpredab, mw2b, nullptr, dsua, NACT, MHID, Dc, MHID, 1.f, 0.f, 0, nullptr);
    dsilu_kernel<<<(NACT * MHID + 255) / 256, 256, 0, stream>>>(dsua, ua, dua, duab, NACT * MHID);
    gdir(0, 0, duab, mw1b, nullptr, dfeata, NACT, FPOLY, MHID, FPOLY, 1.f, 0.f, 0, nullptr);
    dz_kernel<<<NACT, 64, 0, stream>>>(dfeata, za, dza, dzab);

    // transposed bf16 copies for the NS/PT path
    tconv(dua, duaTb, 128, MHID, 128);
    tconv(dpreda, dpredaTb, 128, Dc, 128);
    tconv(dza, dzaTb, 128, HDc, 128);
    tconv(xa, xaTb, 128, Dc, 128);

    // 6. Newton-Schulz in 128x128 space (bf16 MFMA, batched z=3)
    gdir(0, 0, featAb, featAb, nullptr, SA,         128, 128, FPOLY, 128, 1.f, 0.f, 0, nullptr);
    gdir(0, 0, suab,   suab,   nullptr, SA + 16384, 128, 128, MHID,  128, 1.f, 0.f, 0, nullptr);
    gdir(0, 0, xab,    xab,    nullptr, SA + 32768, 128, 128, Dc,    128, 1.f, 0.f, 0, nullptr);
    gdir(0, 0, duab,   duab,   nullptr, CA,         128, 128, MHID,  128, 1.f, 0.f, 0, nullptr);
    gdir(0, 0, dpredab,dpredab,nullptr, CA + 16384, 128, 128, Dc,    128, 1.f, 0.f, 0, nullptr);
    gdir(0, 0, dzab,   dzab,   nullptr, CA + 32768, 128, 128, HDc,   128, 1.f, 0.f, 0, nullptr);
    ns_norm_kernel<<<3, 256, 0, stream>>>(SA, CA, Sb16, Cb16, scal + 8);
    {
        bf16 *fc = FcAb, *fct = FcTAb, *fcn = FcBb, *fctn = FcTBb;
        for (int t = 0; t < 5; ++t) {
            bmm128<1><<<3, 256, 0, stream>>>(Sb16, Cb16, nullptr, Mb16, MTb16, 1.f, 0.f, 0.f);      // M = S@C (C sym)
            bmm128<1><<<3, 256, 0, stream>>>(Mb16, MTb16, Mb16, Fb16, FTb16, 2.0315f, -4.775f, 3.4445f); // F = cM^2+bM+aI
            if (t == 0) copy3_kernel<<<192, 256, 0, stream>>>(Fb16, FTb16, FcAb, FcTAb);
            else {
                bmm128<1><<<3, 256, 0, stream>>>(fc, FTb16, nullptr, fcn, fctn, 1.f, 0.f, 0.f);    // Fc = Fc@F
                bf16* t1 = fc; fc = fcn; fcn = t1;
                bf16* t2 = fct; fct = fctn; fctn = t2;
            }
            if (t < 4) {
                bmm128<1><<<3, 256, 0, stream>>>(Cb16, FTb16, nullptr, Zb16, ZTb16, 1.f, 0.f, 0.f); // Z = C@F
                bmm128<0><<<3, 256, 0, stream>>>(ZTb16, FTb16, nullptr, Cb16, nullptr, 1.f, 0.f, 0.f); // C' = Z^T@F
            }
        }
        // PT^T = PTraw^T @ Fc, scaled by invn (fct = Fc^T row-major = Bt for A@Bt^T)
        gdir(1, 0, duaTb,    fct,         nullptr, PT1Tb, MHID, 128, 128, 128, 1.f, 0.f, 0, scal + 8);
        gdir(1, 0, dpredaTb, fct + 16384, nullptr, PT2Tb, Dc,   128, 128, 128, 1.f, 0.f, 0, scal + 9);
        gdir(1, 0, dzaTb,    fct + 32768, nullptr, PT3Tb, HDc,  128, 128, 128, 1.f, 0.f, 0, scal + 10);
    }
    // wkuT = 0.999*mwkT - 0.01*PT3T@xa   (PT3T already has invn3)
    gdir(1, 1, PT3Tb, xaTb, mwkTb, wkuTb, HDc, Dc, 128, Dc, -0.01f, 0.999f, 0, nullptr);

    // 7. x2 = x + attn@wo; zf = qmem@wku
    gemmB(0, 0, attnb, wowT, x, x2, NTOK, Dc, Dc, Dc, 1.f, 1.f, 0, nullptr);
    cvt_kernel<<<2048, 256, 0, stream>>>(qmem, qmemb, NTOK * Dc);
    gdir(0, 0, qmemb, wkuTb, nullptr, zf, NTOK, HDc, Dc, HDc, 1.f, 0.f, 0, nullptr);

    // 8. memory forward (low-rank updated weights), 2 chunks
    for (int c = 0; c < NTOK / MCH; ++c) {
        const int R = c * MCH;
        phi2_bf16<<<dim3((FPOLY + 255) / 256, MCH), 256, 0, stream>>>(zf + (size_t)R * HDc, featC);
        gemmB(1, 0, featC, mw1T, nullptr, t1b, MCH, MHID, FPOLY, MHID, 0.999f, 0.f, 0, nullptr);
        gdir(1, 0, featC, featAb, nullptr, tBb, MCH, NACT, FPOLY, NACT, 1.f, 0.f, 0, nullptr);
        gdir(1, 1, tBb, PT1Tb, t1b, t1b, MCH, MHID, 128, MHID, -0.01f, 1.f, 1, nullptr);
        gemmB(0, 0, t1b, mw2T, x2 + (size_t)R * Dc, x2 + (size_t)R * Dc,
              MCH, Dc, MHID, Dc, 0.999f, 1.f, 0, scal + 2);
        gdir(1, 0, t1b, suab, nullptr, tBb, MCH, NACT, MHID, NACT, 1.f, 0.f, 0, nullptr);
        gdir(0, 0, tBb, PT2Tb, x2 + (size_t)R * Dc, x2 + (size_t)R * Dc,
             MCH, Dc, 128, Dc, -0.01f, 1.f, 0, scal + 2);
    }
    // 9. FFN (swiglu)
    rms_rows<<<NTOK, 256, 0, stream>>>(x2, n2w, h2b, Dc);
    gemmB(1, 0, h2b, fw1T, nullptr, ff1b, NTOK, FFNH, Dc, FFNHP, 1.f, 0.f, 1, nullptr);
    gemmB(1, 0, h2b, fw3T, nullptr, ff3b, NTOK, FFNH, Dc, FFNHP, 1.f, 0.f, 0, nullptr);
    mulpad_kernel<<<(NTOK * FFNHP + 255) / 256, 256, 0, stream>>>(ff1b, ff3b);
    gemmB(0, 0, ff1b, fw2T, x2, outp, NTOK, Dc, FFNHP, Dc, 1.f, 1.f, 0, nullptr);
}

// Round 6
// 1829.999 us; speedup vs baseline: 1.5638x; 1.5638x over previous
//
#include <hip/hip_runtime.h>
#include <math.h>

#define Bc 2
#define Sc 2048
#define Dc 1024
#define Hc 16
#define HDc 64
#define FPOLY 4160
#define MHID 2048
#define FFNH 2730
#define FFNHP 2752   // FFNH padded to mult of 32 (K pad, zero-filled)
#define GGH 64
#define NTOK 4096
#define NACT 128
#define MCH 2048     // memory-forward M chunk

typedef __bf16 bf16;
typedef __attribute__((ext_vector_type(8))) __bf16 bf16x8;
typedef __attribute__((ext_vector_type(4))) float f32x4;

#define AS1 __attribute__((address_space(1)))
#define AS3 __attribute__((address_space(3)))

__device__ __forceinline__ void gload16(const void* g, void* l) {
    __builtin_amdgcn_global_load_lds((AS1 const void*)g, (AS3 void*)l, 16, 0, 0);
}

// ---------------------------------------------------------------- bf16 MFMA GEMM (LDS, big tiles)
// C = act(alpha*[sptr]*A@Bt^T + beta*Cin).  A:(M,K) bf16 row-major, Bt:(N,K) bf16.
// K%32==0, M%128==0. N arbitrary; Bt rows allocated to ceil(N/128)*128.
template<int OUTBF, int CINBF>
__global__ __launch_bounds__(256) void gemm_bt(
    const bf16* __restrict__ A, const bf16* __restrict__ Bt,
    const void* __restrict__ Cin, void* __restrict__ Cout,
    int M, int N, int K, int ldc,
    float alpha, float beta, int act, const float* __restrict__ sptr)
{
    __shared__ bf16 As[128 * 32];
    __shared__ bf16 Bs[128 * 32];
    const int tid = threadIdx.x;
    const int w = tid >> 6, lane = tid & 63;
    const int bm = blockIdx.y * 128, bn = blockIdx.x * 128;
    const int wm = (w >> 1) * 64, wn = (w & 1) * 64;
    f32x4 acc[4][4];
#pragma unroll
    for (int i = 0; i < 4; ++i)
#pragma unroll
        for (int j = 0; j < 4; ++j) { acc[i][j][0] = 0.f; acc[i][j][1] = 0.f; acc[i][j][2] = 0.f; acc[i][j][3] = 0.f; }
    const int idx0 = tid, idx1 = tid + 256;
    const int r0 = idx0 >> 2, r1 = idx1 >> 2;
    const int g0 = ((idx0 & 3) ^ ((r0 >> 1) & 3)) * 8;
    const int g1 = ((idx1 & 3) ^ ((r1 >> 1) & 3)) * 8;
    char* ldsA0 = (char*)As + w * 1024;
    char* ldsB0 = (char*)Bs + w * 1024;
    const int lrow = lane & 15;
    const int q = lane >> 4;
    int aoff[4], boff[4];
#pragma unroll
    for (int t = 0; t < 4; ++t) {
        int ar = wm + t * 16 + lrow;
        aoff[t] = ar * 32 + ((q ^ ((ar >> 1) & 3)) * 8);
        int br = wn + t * 16 + lrow;
        boff[t] = br * 32 + ((q ^ ((br >> 1) & 3)) * 8);
    }
    const bf16* Arow0 = A + (size_t)(bm + r0) * K + g0;
    const bf16* Arow1 = A + (size_t)(bm + r1) * K + g1;
    const bf16* Brow0 = Bt + (size_t)(bn + r0) * K + g0;
    const bf16* Brow1 = Bt + (size_t)(bn + r1) * K + g1;
    for (int k0 = 0; k0 < K; k0 += 32) {
        gload16(Arow0 + k0, ldsA0);
        gload16(Arow1 + k0, ldsA0 + 4096);
        gload16(Brow0 + k0, ldsB0);
        gload16(Brow1 + k0, ldsB0 + 4096);
        __syncthreads();
        bf16x8 af[4], bfr[4];
#pragma unroll
        for (int t = 0; t < 4; ++t) af[t] = *(const bf16x8*)&As[aoff[t]];
#pragma unroll
        for (int t = 0; t < 4; ++t) bfr[t] = *(const bf16x8*)&Bs[boff[t]];
#pragma unroll
        for (int mt = 0; mt < 4; ++mt)
#pragma unroll
            for (int nt = 0; nt < 4; ++nt)
                acc[mt][nt] = __builtin_amdgcn_mfma_f32_16x16x32_bf16(af[mt], bfr[nt], acc[mt][nt], 0, 0, 0);
        __syncthreads();
    }
    const float amul = alpha * (sptr ? *sptr : 1.f);
#pragma unroll
    for (int nt = 0; nt < 4; ++nt) {
        const int col = bn + wn + nt * 16 + lrow;
        if (col >= N) continue;
#pragma unroll
        for (int mt = 0; mt < 4; ++mt) {
            const int rbase = bm + wm + mt * 16 + q * 4;
#pragma unroll
            for (int r = 0; r < 4; ++r) {
                const size_t o = (size_t)(rbase + r) * ldc + col;
                float v = amul * acc[mt][nt][r];
                if (beta != 0.f)
                    v += beta * (CINBF ? (float)((const bf16*)Cin)[o] : ((const float*)Cin)[o]);
                if (act == 1) v = v / (1.f + __expf(-v));
                if (OUTBF) ((bf16*)Cout)[o] = (bf16)v;
                else       ((float*)Cout)[o] = v;
            }
        }
    }
}

// ---------------------------------------------------------------- barrier-free direct MFMA GEMM
// Block = 128 rows (4 waves x 32) x 128 cols. Rows beyond M/N must be ALLOCATED readable.
template<int OUTBF, int CINBF>
__global__ __launch_bounds__(256) void gemm_direct(
    const bf16* __restrict__ A, const bf16* __restrict__ Bt,
    const void* __restrict__ Cin, void* __restrict__ Cout,
    int M, int N, int K, int ldc,
    float alpha, float beta, int act, const float* __restrict__ sptr)
{
    const int tid = threadIdx.x, w = tid >> 6, lane = tid & 63;
    const int lrow = lane & 15, quad = lane >> 4;
    const int bm = blockIdx.y * 128 + w * 32;
    const int bn = blockIdx.x * 128;
    f32x4 acc[2][8];
#pragma unroll
    for (int mt = 0; mt < 2; ++mt)
#pragma unroll
        for (int nt = 0; nt < 8; ++nt) { acc[mt][nt][0] = 0.f; acc[mt][nt][1] = 0.f; acc[mt][nt][2] = 0.f; acc[mt][nt][3] = 0.f; }
    const bf16* Abase = A + (size_t)(bm + lrow) * K + quad * 8;
    const bf16* Bbase = Bt + (size_t)(bn + lrow) * K + quad * 8;
#pragma unroll 2
    for (int k0 = 0; k0 < K; k0 += 32) {
        bf16x8 af0 = *(const bf16x8*)(Abase + k0);
        bf16x8 af1 = *(const bf16x8*)(Abase + (size_t)16 * K + k0);
#pragma unroll
        for (int nt = 0; nt < 8; ++nt) {
            bf16x8 bfr = *(const bf16x8*)(Bbase + (size_t)nt * 16 * K + k0);
            acc[0][nt] = __builtin_amdgcn_mfma_f32_16x16x32_bf16(af0, bfr, acc[0][nt], 0, 0, 0);
            acc[1][nt] = __builtin_amdgcn_mfma_f32_16x16x32_bf16(af1, bfr, acc[1][nt], 0, 0, 0);
        }
    }
    const float amul = alpha * (sptr ? *sptr : 1.f);
#pragma unroll
    for (int nt = 0; nt < 8; ++nt) {
        const int col = bn + nt * 16 + lrow;
        if (col >= N) continue;
#pragma unroll
        for (int mt = 0; mt < 2; ++mt) {
            const int rbase = bm + mt * 16 + quad * 4;
#pragma unroll
            for (int r = 0; r < 4; ++r) {
                const int row = rbase + r;
                if (row >= M) continue;
                const size_t o = (size_t)row * ldc + col;
                float v = amul * acc[mt][nt][r];
                if (beta != 0.f)
                    v += beta * (CINBF ? (float)((const bf16*)Cin)[o] : ((const float*)Cin)[o]);
                if (act == 1) v = v / (1.f + __expf(-v));
                if (OUTBF) ((bf16*)Cout)[o] = (bf16)v;
                else       ((float*)Cout)[o] = v;
            }
        }
    }
}

// ---------------------------------------------------------------- split-K direct GEMM
// part[z] = A @ Bt^T over K-chunk z (KC wide, KC%32==0). fp32 partials, no epilogue.
__global__ __launch_bounds__(256) void gemm_skp(
    const bf16* __restrict__ A, const bf16* __restrict__ Bt,
    float* __restrict__ part, int M, int N, int K, int KC)
{
    const int tid = threadIdx.x, w = tid >> 6, lane = tid & 63;
    const int lrow = lane & 15, quad = lane >> 4;
    const int bm = blockIdx.y * 128 + w * 32;
    const int bn = blockIdx.x * 128;
    const int z = blockIdx.z;
    const int kb = z * KC;
    int ke = kb + KC; if (ke > K) ke = K;
    f32x4 acc[2][8];
#pragma unroll
    for (int mt = 0; mt < 2; ++mt)
#pragma unroll
        for (int nt = 0; nt < 8; ++nt) { acc[mt][nt][0] = 0.f; acc[mt][nt][1] = 0.f; acc[mt][nt][2] = 0.f; acc[mt][nt][3] = 0.f; }
    const bf16* Abase = A + (size_t)(bm + lrow) * K + quad * 8;
    const bf16* Bbase = Bt + (size_t)(bn + lrow) * K + quad * 8;
#pragma unroll 2
    for (int k0 = kb; k0 < ke; k0 += 32) {
        bf16x8 af0 = *(const bf16x8*)(Abase + k0);
        bf16x8 af1 = *(const bf16x8*)(Abase + (size_t)16 * K + k0);
#pragma unroll
        for (int nt = 0; nt < 8; ++nt) {
            bf16x8 bfr = *(const bf16x8*)(Bbase + (size_t)nt * 16 * K + k0);
            acc[0][nt] = __builtin_amdgcn_mfma_f32_16x16x32_bf16(af0, bfr, acc[0][nt], 0, 0, 0);
            acc[1][nt] = __builtin_amdgcn_mfma_f32_16x16x32_bf16(af1, bfr, acc[1][nt], 0, 0, 0);
        }
    }
    float* po = part + (size_t)z * M * N;
#pragma unroll
    for (int nt = 0; nt < 8; ++nt) {
        const int col = bn + nt * 16 + lrow;
        if (col >= N) continue;
#pragma unroll
        for (int mt = 0; mt < 2; ++mt) {
            const int rbase = bm + mt * 16 + quad * 4;
#pragma unroll
            for (int r = 0; r < 4; ++r) {
                const int row = rbase + r;
                if (row >= M) continue;
                po[(size_t)row * N + col] = acc[mt][nt][r];
            }
        }
    }
}

__global__ void skred(const float* __restrict__ part, float* __restrict__ out,
                      int SK, int MN)
{
    int i = blockIdx.x * 256 + threadIdx.x;
    if (i >= MN) return;
    float s = 0.f;
    for (int z = 0; z < SK; ++z) s += part[(size_t)z * MN + i];
    out[i] = s;
}

// ---------------------------------------------------------------- polynomial-kernel gram
// S = G + G^2/64 where G = za@za^T, za (128x64) fp32. phi(x).phi(y) = x.y + (x.y)^2/64.
__global__ __launch_bounds__(256) void gram_trick(
    const float* __restrict__ za, float* __restrict__ S)
{
    __shared__ float z[128 * 65];
    for (int i = threadIdx.x; i < 8192; i += 256) {
        int r = i >> 6, d = i & 63;
        z[r * 65 + d] = za[i];
    }
    __syncthreads();
    for (int idx = threadIdx.x; idx < 16384; idx += 256) {
        int i = idx >> 7, j = idx & 127;
        float dot = 0.f;
#pragma unroll
        for (int d = 0; d < 64; ++d) dot += z[i * 65 + d] * z[j * 65 + d];
        S[idx] = dot + dot * dot * 0.015625f;
    }
}

// ---------------------------------------------------------------- batched 128x128x128 bf16 MFMA
template<int DUALT>
__global__ __launch_bounds__(256) void bmm128(
    const bf16* __restrict__ Ab, const bf16* __restrict__ Btb,
    const bf16* __restrict__ Minb, bf16* __restrict__ Cb, bf16* __restrict__ CTb,
    float alpha, float beta, float dg)
{
    const int z = blockIdx.x;
    const bf16* A = Ab + (size_t)z * 16384;
    const bf16* Bt = Btb + (size_t)z * 16384;
    const int tid = threadIdx.x, w = tid >> 6, lane = tid & 63;
    const int lrow = lane & 15, quad = lane >> 4;
    const int bm = w * 32;
    f32x4 acc[2][8];
#pragma unroll
    for (int mt = 0; mt < 2; ++mt)
#pragma unroll
        for (int nt = 0; nt < 8; ++nt) { acc[mt][nt][0] = 0.f; acc[mt][nt][1] = 0.f; acc[mt][nt][2] = 0.f; acc[mt][nt][3] = 0.f; }
#pragma unroll
    for (int k0 = 0; k0 < 128; k0 += 32) {
        bf16x8 af0 = *(const bf16x8*)(A + (size_t)(bm + lrow) * 128 + k0 + quad * 8);
        bf16x8 af1 = *(const bf16x8*)(A + (size_t)(bm + 16 + lrow) * 128 + k0 + quad * 8);
#pragma unroll
        for (int nt = 0; nt < 8; ++nt) {
            bf16x8 bfr = *(const bf16x8*)(Bt + (size_t)(nt * 16 + lrow) * 128 + k0 + quad * 8);
            acc[0][nt] = __builtin_amdgcn_mfma_f32_16x16x32_bf16(af0, bfr, acc[0][nt], 0, 0, 0);
            acc[1][nt] = __builtin_amdgcn_mfma_f32_16x16x32_bf16(af1, bfr, acc[1][nt], 0, 0, 0);
        }
    }
#pragma unroll
    for (int nt = 0; nt < 8; ++nt) {
        const int col = nt * 16 + lrow;
#pragma unroll
        for (int mt = 0; mt < 2; ++mt) {
#pragma unroll
            for (int r = 0; r < 4; ++r) {
                const int row = bm + mt * 16 + quad * 4 + r;
                float v = alpha * acc[mt][nt][r];
                if (beta != 0.f) v += beta * (float)Minb[(size_t)z * 16384 + row * 128 + col];
                if (dg != 0.f && row == col) v += dg;
                Cb[(size_t)z * 16384 + row * 128 + col] = (bf16)v;
                if (DUALT) CTb[(size_t)z * 16384 + col * 128 + row] = (bf16)v;
            }
        }
    }
}

__global__ void copy3_kernel(const bf16* __restrict__ a, const bf16* __restrict__ b,
                             bf16* __restrict__ ca, bf16* __restrict__ cb)
{
    int i = blockIdx.x * 256 + threadIdx.x;
    ca[i] = a[i]; cb[i] = b[i];
}

// per-batch: n2 = <S[z],C[z]>; Cb=bf16(C/n2); Sb=bf16(S); invn[z] = 1/(sqrt(n2)+1e-7)
__global__ __launch_bounds__(256) void ns_norm_kernel(
    const float* __restrict__ S, const float* __restrict__ C,
    bf16* __restrict__ Sb, bf16* __restrict__ Cb, float* __restrict__ invn)
{
    const int z = blockIdx.x;
    const float* s = S + (size_t)z * 16384;
    const float* c = C + (size_t)z * 16384;
    float acc = 0.f;
    for (int i = threadIdx.x; i < 16384; i += 256) acc += s[i] * c[i];
    __shared__ float red[256];
    red[threadIdx.x] = acc; __syncthreads();
    for (int st = 128; st; st >>= 1) {
        if (threadIdx.x < st) red[threadIdx.x] += red[threadIdx.x + st];
        __syncthreads();
    }
    float inv = 1.f / (sqrtf(red[0]) + 1e-7f);
    float inv2 = inv * inv;
    for (int i = threadIdx.x; i < 16384; i += 256) {
        Cb[(size_t)z * 16384 + i] = (bf16)(c[i] * inv2);
        Sb[(size_t)z * 16384 + i] = (bf16)s[i];
    }
    if (threadIdx.x == 0) invn[z] = inv;
}

// ---------------------------------------------------------------- converts
__global__ __launch_bounds__(256) void tconv_kernel(
    const float* __restrict__ W, bf16* __restrict__ Wt, int K, int N, int Kpad)
{
    __shared__ float t[32][33];
    const int k0 = blockIdx.x * 32, n0 = blockIdx.y * 32;
    const int tx = threadIdx.x & 31, ty = threadIdx.x >> 5;
#pragma unroll
    for (int r = 0; r < 4; ++r) {
        int gk = k0 + ty + r * 8, gn = n0 + tx;
        t[ty + r * 8][tx] = (gk < K && gn < N) ? W[(size_t)gk * N + gn] : 0.f;
    }
    __syncthreads();
#pragma unroll
    for (int r = 0; r < 4; ++r) {
        int gn = n0 + ty + r * 8, gk = k0 + tx;
        if (gn < N && gk < Kpad) Wt[(size_t)gn * Kpad + gk] = (bf16)t[tx][ty + r * 8];
    }
}

__global__ void cvt_kernel(const float* __restrict__ in, bf16* __restrict__ out, int n)
{
    for (int i = blockIdx.x * 256 + threadIdx.x; i < n; i += gridDim.x * 256)
        out[i] = (bf16)in[i];
}

// vb (b,s,h,d) -> vt (b,h,d,s)
__global__ __launch_bounds__(256) void vtrans_kernel(
    const bf16* __restrict__ vb, bf16* __restrict__ vt)
{
    __shared__ bf16 t[32][33];
    const int s0 = blockIdx.x * 32, d0 = blockIdx.y * 32, bh = blockIdx.z;
    const int b = bh >> 4, h = bh & 15;
    const int tx = threadIdx.x & 31, ty = threadIdx.x >> 5;
#pragma unroll
    for (int r = 0; r < 4; ++r) {
        int s = s0 + ty + r * 8;
        t[ty + r * 8][tx] = vb[((size_t)b * Sc + s) * Dc + h * 64 + d0 + tx];
    }
    __syncthreads();
#pragma unroll
    for (int r = 0; r < 4; ++r) {
        int d = d0 + ty + r * 8;
        vt[((size_t)bh * 64 + d) * Sc + s0 + tx] = t[tx][ty + r * 8];
    }
}

// ---------------------------------------------------------------- small kernels
__global__ __launch_bounds__(256) void rms_rows(
    const float* __restrict__ in, const float* __restrict__ w,
    bf16* __restrict__ out, int D)
{
    const int row = blockIdx.x;
    const float* r = in + (size_t)row * D;
    bf16* o = out + (size_t)row * D;
    float s = 0.f;
    for (int i = threadIdx.x; i < D; i += 256) { float v = r[i]; s += v * v; }
    __shared__ float red[256];
    red[threadIdx.x] = s;
    __syncthreads();
    for (int st = 128; st; st >>= 1) {
        if (threadIdx.x < st) red[threadIdx.x] += red[threadIdx.x + st];
        __syncthreads();
    }
    float rs = rsqrtf(red[0] / (float)D + 1e-6f);
    for (int i = threadIdx.x; i < D; i += 256) o[i] = (bf16)(r[i] * rs * w[i]);
}

__global__ __launch_bounds__(256) void gamma_kernel(
    const float* __restrict__ gg1, const float* __restrict__ w2,
    float* __restrict__ gamma)
{
    const int tid = threadIdx.x, w = tid >> 6, lane = tid & 63;
    const int t = blockIdx.x * 4 + w;
    float v = gg1[(size_t)t * GGH + lane];
    v = v / (1.f + expf(-v));
    v *= w2[lane];
#pragma unroll
    for (int off = 32; off; off >>= 1) v += __shfl_xor(v, off);
    if (lane == 0) gamma[t] = 1.f / (1.f + expf(-v));
}

__global__ __launch_bounds__(256) void snr_one(
    const bf16* __restrict__ src, const float* __restrict__ w,
    bf16* __restrict__ dst)
{
    const int tid = threadIdx.x, wv = tid >> 6, lane = tid & 63;
    const int s = blockIdx.x * 4 + wv;
    const int h = blockIdx.y, b = blockIdx.z;
    const size_t row = ((size_t)b * Sc + s) * Dc + h * 64;
    float v = (float)src[row + lane];
    float ss = v * v;
#pragma unroll
    for (int off = 32; off; off >>= 1) ss += __shfl_xor(ss, off);
    v = v * rsqrtf(ss / 64.f + 1e-6f) * w[lane];
    const int j = lane & 31;
    float inv = powf(10000.f, -(float)j / 32.f);
    float ang = (float)s * inv;
    float sn = sinf(ang), cs = cosf(ang);
    float p = __shfl_xor(v, 32);
    float o;
    if (lane < 32) o = v * cs - p * sn;
    else           o = p * sn + v * cs;
    const size_t od = (((size_t)b * Hc + h) * Sc + s) * 64 + lane;
    dst[od] = (bf16)o;
}

__global__ void kpsum_kernel(const bf16* __restrict__ kn, float* __restrict__ psum)
{
    const int bh = blockIdx.x, c = blockIdx.y, d = threadIdx.x;
    const size_t base = (size_t)bh * Sc * 64 + (size_t)c * 128 * 64 + d;
    float s = 0.f;
    for (int i = 0; i < 128; ++i) s += (float)kn[base + (size_t)i * 64];
    psum[((size_t)bh * 16 + c) * 64 + d] = s;
}

__global__ void qmem2_kernel(
    const bf16* __restrict__ qn, const bf16* __restrict__ kn,
    const float* __restrict__ gamma, const float* __restrict__ psum,
    float* __restrict__ qmem)
{
    const int bh = blockIdx.x, c = blockIdx.y;
    const int b = bh >> 4, hh = bh & 15;
    const int d = threadIdx.x;
    const size_t base = (size_t)bh * Sc * 64;
    float run = 0.f;
    for (int cc = 0; cc < c; ++cc) run += psum[((size_t)bh * 16 + cc) * 64 + d];
    for (int s = c * 128; s < c * 128 + 128; ++s) {
        run += (float)kn[base + (size_t)s * 64 + d];
        float cm = run / (float)(s + 1);
        float g = gamma[b * Sc + s];
        float qv = (float)qn[base + (size_t)s * 64 + d];
        qmem[((size_t)(b * Sc + s)) * Dc + hh * 64 + d] = g * qv + (1.f - g) * cm;
    }
}

// ---------------------------------------------------------------- MFMA flash attention
__global__ __launch_bounds__(256) void attn_mfma(
    const bf16* __restrict__ qn, const bf16* __restrict__ kn,
    const bf16* __restrict__ vt, bf16* __restrict__ outp)
{
    const int qt = blockIdx.x;
    const int h = blockIdx.y, b = blockIdx.z;
    const int bh = b * Hc + h;
    const int tid = threadIdx.x, w = tid >> 6, lane = tid & 63;
    const int lrow = lane & 15, quad = lane >> 4;
    const int qb = qt * 128;
    const int wq = w * 32;
    __shared__ bf16 Ps[4][32][136];
    bf16x8 qf[2][2];
    const bf16* qbase = qn + ((size_t)bh * Sc + qb + wq) * 64;
#pragma unroll
    for (int mt = 0; mt < 2; ++mt)
#pragma unroll
        for (int ks = 0; ks < 2; ++ks)
            qf[mt][ks] = *(const bf16x8*)(qbase + (size_t)(mt * 16 + lrow) * 64 + ks * 32 + quad * 8);
    f32x4 oacc[2][4];
#pragma unroll
    for (int mt = 0; mt < 2; ++mt)
#pragma unroll
        for (int nt = 0; nt < 4; ++nt) { oacc[mt][nt][0] = 0.f; oacc[mt][nt][1] = 0.f; oacc[mt][nt][2] = 0.f; oacc[mt][nt][3] = 0.f; }
    float m_i[2][4], l_i[2][4];
#pragma unroll
    for (int mt = 0; mt < 2; ++mt)
#pragma unroll
        for (int r = 0; r < 4; ++r) { m_i[mt][r] = -1e30f; l_i[mt][r] = 0.f; }
    const bf16* kbase = kn + (size_t)bh * Sc * 64;
    const bf16* vtb = vt + (size_t)bh * 64 * Sc;
    for (int k0 = 0; k0 <= qb; k0 += 128) {
        f32x4 sacc[2][8];
#pragma unroll
        for (int mt = 0; mt < 2; ++mt)
#pragma unroll
            for (int nt = 0; nt < 8; ++nt) { sacc[mt][nt][0] = 0.f; sacc[mt][nt][1] = 0.f; sacc[mt][nt][2] = 0.f; sacc[mt][nt][3] = 0.f; }
#pragma unroll
        for (int ks = 0; ks < 2; ++ks) {
            bf16x8 kf[8];
#pragma unroll
            for (int nt = 0; nt < 8; ++nt)
                kf[nt] = *(const bf16x8*)(kbase + (size_t)(k0 + nt * 16 + lrow) * 64 + ks * 32 + quad * 8);
#pragma unroll
            for (int mt = 0; mt < 2; ++mt)
#pragma unroll
                for (int nt = 0; nt < 8; ++nt)
                    sacc[mt][nt] = __builtin_amdgcn_mfma_f32_16x16x32_bf16(qf[mt][ks], kf[nt], sacc[mt][nt], 0, 0, 0);
        }
        const bool diag = (k0 == qb);
#pragma unroll
        for (int mt = 0; mt < 2; ++mt) {
            float mx[4] = {-1e30f, -1e30f, -1e30f, -1e30f};
#pragma unroll
            for (int nt = 0; nt < 8; ++nt) {
                int kc = k0 + nt * 16 + lrow;
#pragma unroll
                for (int r = 0; r < 4; ++r) {
                    float v = sacc[mt][nt][r] * 0.125f;
                    if (diag && kc > qb + wq + mt * 16 + quad * 4 + r) v = -1e30f;
                    sacc[mt][nt][r] = v;
                    mx[r] = fmaxf(mx[r], v);
                }
            }
#pragma unroll
            for (int r = 0; r < 4; ++r) {
#pragma unroll
                for (int off = 1; off < 16; off <<= 1) mx[r] = fmaxf(mx[r], __shfl_xor(mx[r], off));
                float mnew = fmaxf(m_i[mt][r], mx[r]);
                float corr = __expf(m_i[mt][r] - mnew);
                m_i[mt][r] = mnew;
                l_i[mt][r] *= corr;
#pragma unroll
                for (int nt2 = 0; nt2 < 4; ++nt2) oacc[mt][nt2][r] *= corr;
            }
            float sum[4] = {0.f, 0.f, 0.f, 0.f};
#pragma unroll
            for (int nt = 0; nt < 8; ++nt)
#pragma unroll
                for (int r = 0; r < 4; ++r) {
                    float p = __expf(sacc[mt][nt][r] - m_i[mt][r]);
                    sacc[mt][nt][r] = p;
                    sum[r] += p;
                }
#pragma unroll
            for (int r = 0; r < 4; ++r) {
#pragma unroll
                for (int off = 1; off < 16; off <<= 1) sum[r] += __shfl_xor(sum[r], off);
                l_i[mt][r] += sum[r];
            }
#pragma unroll
            for (int nt = 0; nt < 8; ++nt)
#pragma unroll
                for (int r = 0; r < 4; ++r)
                    Ps[w][mt * 16 + quad * 4 + r][nt * 16 + lrow] = (bf16)sacc[mt][nt][r];
        }
#pragma unroll
        for (int ks = 0; ks < 4; ++ks) {
            bf16x8 pf[2];
#pragma unroll
            for (int mt = 0; mt < 2; ++mt)
                pf[mt] = *(const bf16x8*)&Ps[w][mt * 16 + lrow][ks * 32 + quad * 8];
#pragma unroll
            for (int nt = 0; nt < 4; ++nt) {
                bf16x8 vf = *(const bf16x8*)(vtb + (size_t)(nt * 16 + lrow) * Sc + k0 + ks * 32 + quad * 8);
#pragma unroll
                for (int mt = 0; mt < 2; ++mt)
                    oacc[mt][nt] = __builtin_amdgcn_mfma_f32_16x16x32_bf16(pf[mt], vf, oacc[mt][nt], 0, 0, 0);
            }
        }
    }
#pragma unroll
    for (int mt = 0; mt < 2; ++mt)
#pragma unroll
        for (int nt = 0; nt < 4; ++nt)
#pragma unroll
            for (int r = 0; r < 4; ++r) {
                int row = qb + wq + mt * 16 + quad * 4 + r;
                int dcol = nt * 16 + lrow;
                outp[((size_t)b * Sc + row) * Dc + h * 64 + dcol] = (bf16)(oacc[mt][nt][r] / l_i[mt][r]);
            }
}

__global__ __launch_bounds__(256) void gather_active(
    const float* __restrict__ qmem, const bf16* __restrict__ vbuf,
    float* __restrict__ xa, bf16* __restrict__ xab, float* __restrict__ va)
{
    const int t = blockIdx.x;
    const int b = t >> 6;
    const int s = Sc - 64 + (t & 63);
    const float* qrow = qmem + ((size_t)(b * Sc + s)) * Dc;
    const bf16* vrow = vbuf + ((size_t)(b * Sc + s)) * Dc;
    for (int i = threadIdx.x; i < Dc; i += 256) {
        float q = qrow[i];
        xa[(size_t)t * Dc + i] = q;
        xab[(size_t)t * Dc + i] = (bf16)q;
        va[(size_t)t * Dc + i] = (float)vrow[i];
    }
}

__global__ void wvec_kernel(const float* __restrict__ gamma,
                            float* __restrict__ wvec, float* __restrict__ wsum)
{
    const int t = threadIdx.x;
    const int b = t >> 6, si = t & 63;
    const int s = Sc - 64 + si;
    float v = gamma[b * Sc + s] * powf(0.95f, (float)(Sc - 1 - s));
    wvec[t] = v;
    __shared__ float red[128];
    red[t] = v; __syncthreads();
    for (int st = 64; st; st >>= 1) { if (t < st) red[t] += red[t + st]; __syncthreads(); }
    if (t == 0) wsum[0] = red[0];
}

__global__ __launch_bounds__(256) void phi2_f32(
    const float* __restrict__ z, float* __restrict__ feat, bf16* __restrict__ featb)
{
    const int f = blockIdx.x * 256 + threadIdx.x;
    const int t = blockIdx.y;
    if (f >= FPOLY) return;
    const float* zr = z + (size_t)t * 64;
    float v;
    if (f < 64) v = zr[f];
    else { int i = (f - 64) >> 6, j = (f - 64) & 63; v = zr[i] * zr[j] * 0.125f; }
    feat[(size_t)t * FPOLY + f] = v;
    featb[(size_t)t * FPOLY + f] = (bf16)v;
}

__global__ __launch_bounds__(256) void phi2_bf16(
    const float* __restrict__ z, bf16* __restrict__ feat)
{
    const int f = blockIdx.x * 256 + threadIdx.x;
    const int t = blockIdx.y;
    if (f >= FPOLY) return;
    const float* zr = z + (size_t)t * 64;
    float v;
    if (f < 64) v = zr[f];
    else { int i = (f - 64) >> 6, j = (f - 64) & 63; v = zr[i] * zr[j] * 0.125f; }
    feat[(size_t)t * FPOLY + f] = (bf16)v;
}

__global__ void silu_kernel(const float* __restrict__ in, float* __restrict__ out,
                            bf16* __restrict__ outb, int n)
{
    int i = blockIdx.x * 256 + threadIdx.x;
    if (i < n) {
        float v = in[i];
        float s = v / (1.f + expf(-v));
        out[i] = s; outb[i] = (bf16)s;
    }
}

__global__ void dpred_kernel(const float* __restrict__ pred, const float* __restrict__ va,
                             const float* __restrict__ wvec, const float* __restrict__ wsum,
                             float* __restrict__ dpred, bf16* __restrict__ dpredb)
{
    int i = blockIdx.x * 256 + threadIdx.x;
    if (i < NACT * Dc) {
        int t = i >> 10;
        float v = 2.f * wvec[t] / (wsum[0] + 1e-8f) * (pred[i] - va[i]);
        dpred[i] = v; dpredb[i] = (bf16)v;
    }
}

__global__ void dsilu_kernel(const float* __restrict__ dsu, const float* __restrict__ u,
                             float* __restrict__ du, bf16* __restrict__ dub, int n)
{
    int i = blockIdx.x * 256 + threadIdx.x;
    if (i < n) {
        float uv = u[i];
        float sg = 1.f / (1.f + expf(-uv));
        float v = dsu[i] * sg * (1.f + uv * (1.f - sg));
        du[i] = v; dub[i] = (bf16)v;
    }
}

__global__ void dz_kernel(const float* __restrict__ dfeat, const float* __restrict__ za,
                          float* __restrict__ dz, bf16* __restrict__ dzb)
{
    const int t = blockIdx.x;
    const int k = threadIdx.x;
    const float* df = dfeat + (size_t)t * FPOLY;
    const float* z = za + (size_t)t * 64;
    float s1 = 0.f, s2 = 0.f;
    for (int j = 0; j < 64; ++j) {
        float zj = z[j];
        s1 += df[64 + k * 64 + j] * zj;
        s2 += df[64 + j * 64 + k] * zj;
    }
    float v = df[k] + 0.125f * (s1 + s2);
    dz[(size_t)t * 64 + k] = v;
    dzb[(size_t)t * 64 + k] = (bf16)v;
}

__global__ void sgate_kernel(const float* __restrict__ mg, float* __restrict__ out)
{
    out[0] = 1.f / (1.f + expf(-mg[0]));
}

__global__ void mulpad_kernel(bf16* __restrict__ a, const bf16* __restrict__ b)
{
    int i = blockIdx.x * 256 + threadIdx.x;
    if (i >= NTOK * FFNHP) return;
    int k = i % FFNHP;
    if (k >= FFNH) { a[i] = (bf16)0.f; return; }
    a[i] = (bf16)((float)a[i] * (float)b[i]);
}

// ---------------------------------------------------------------- launch
extern "C" void kernel_launch(void* const* d_in, const int* in_sizes, int n_in,
                              void* d_out, int out_size, void* d_ws, size_t ws_size,
                              hipStream_t stream)
{
    const float* x     = (const float*)d_in[0];
    const float* n1w   = (const float*)d_in[1];
    const float* n2w   = (const float*)d_in[2];
    const float* qkvw  = (const float*)d_in[3];
    const float* qnw   = (const float*)d_in[4];
    const float* knw   = (const float*)d_in[5];
    const float* gw1   = (const float*)d_in[6];
    const float* gw2   = (const float*)d_in[7];
    const float* mwk   = (const float*)d_in[8];
    const float* mw1   = (const float*)d_in[9];
    const float* mw2   = (const float*)d_in[10];
    const float* mgate = (const float*)d_in[11];
    const float* wow   = (const float*)d_in[12];
    const float* fw1   = (const float*)d_in[13];
    const float* fw2   = (const float*)d_in[14];
    const float* fw3   = (const float*)d_in[15];
    float* outp = (float*)d_out;

    char* base = (char*)d_ws;
    size_t off = 0;
    auto takeB = [&](size_t bytes) { char* p = base + off; off += (bytes + 255) & ~(size_t)255; return p; };

    // slabs (liveness-overlaid)
    char* slabA  = takeB(22544384);  // partials (stages 2,5,6) / vt (stage 3) -> featC -> ff1b
    char* slabBC = takeB(16777216);  // qnb+knb -> x2 fp32
    char* slabD  = takeB(8388608);   // vb -> t1b
    char* slabE  = takeB(22544384);  // qmem fp32 (16.8M) -> ff3b (22.5M)
    char* slabF  = takeB(8388608);   // qtb -> attnb -> qmemb
    char* slabG  = takeB(17301504);  // hb (8.4M) -> mw1b (17.3M, 4224 rows) -> w1uT (17.04M) -> h2b
    float* partA = (float*)slabA;
    bf16* vt    = (bf16*)slabA;  bf16* featC = (bf16*)slabA;  bf16* ff1b = (bf16*)slabA;
    bf16* qnb = (bf16*)slabBC;   bf16* knb = (bf16*)(slabBC + 8388608);
    float* x2 = (float*)slabBC;
    bf16* vb = (bf16*)slabD;     bf16* t1b = (bf16*)slabD;
    float* qmem = (float*)slabE; bf16* ff3b = (bf16*)slabE;
    bf16* qtb = (bf16*)slabF;    bf16* attnb = (bf16*)slabF;  bf16* qmemb = (bf16*)slabF;
    bf16* hb = (bf16*)slabG;     bf16* mw1b = (bf16*)slabG;
    bf16* w1uT = (bf16*)slabG;   bf16* h2b = (bf16*)slabG;

    // bf16 weights
    bf16* qkvwT = (bf16*)takeB(6291456);
    bf16* gw1T  = (bf16*)takeB(262144);    // 128 rows alloc / 64 real
    bf16* wowT  = (bf16*)takeB(2097152);
    bf16* mw1T  = (bf16*)takeB(17039360);
    bf16* mw2T  = (bf16*)takeB(4194304);
    bf16* fw1T  = (bf16*)takeB(5767168);
    bf16* fw3T  = (bf16*)takeB(5767168);
    bf16* fw2T  = (bf16*)takeB(5636096);
    bf16* mw2b  = (bf16*)takeB(4194304);   // straight copy (2048,1024)
    bf16* mwkTb = (bf16*)takeB(262144);    // (64 real/128 alloc, 1024)
    bf16* wkuTb = (bf16*)takeB(262144);
    bf16* w2uT  = (bf16*)takeB(4194304);   // (1024, 2048)

    // fp32 misc
    float* zf    = (float*)takeB(1048576);
    float* gg1   = (float*)takeB(1048576);
    float* gamma = (float*)takeB(16384);
    float* wvec  = (float*)takeB(512);
    float* scal  = (float*)takeB(256);     // [0]=wsum [2]=sig(gate) [8..10]=invn
    float* psum  = (float*)takeB(131072);
    float* xa    = (float*)takeB(524288);
    float* va    = (float*)takeB(524288);
    float* za    = (float*)takeB(32768);
    float* featA = (float*)takeB(2129920);
    float* ua    = (float*)takeB(1048576);
    float* sua   = (float*)takeB(1048576);
    float* preda = (float*)takeB(524288);
    float* dpreda= (float*)takeB(524288);
    float* dsua  = (float*)takeB(1048576);
    float* dua   = (float*)takeB(1048576);
    float* dfeata= (float*)takeB(2129920);
    float* dza   = (float*)takeB(32768);
    float* SA    = (float*)takeB(196608);  // 3 x 128x128 fp32
    float* CA    = (float*)takeB(196608);
    // bf16 misc
    bf16* featAb = (bf16*)takeB(1064960);
    bf16* suab   = (bf16*)takeB(524288);
    bf16* xab    = (bf16*)takeB(262144);
    bf16* duab   = (bf16*)takeB(524288);
    bf16* dpredab= (bf16*)takeB(262144);
    bf16* dzab   = (bf16*)takeB(16384);
    bf16* PT1Tb  = (bf16*)takeB(524288);   // (2048,128) = P5 for w1
    bf16* PT2Tb  = (bf16*)takeB(262144);   // (1024,128) = P5 for w2
    bf16* PT3Tb  = (bf16*)takeB(32768);
    bf16* duaTb  = (bf16*)takeB(524288);
    bf16* dpredaTb=(bf16*)takeB(262144);
    bf16* dzaTb  = (bf16*)takeB(32768);
    bf16* xaTb   = (bf16*)takeB(262144);
    bf16* featATb= (bf16*)takeB(1081344);  // (4224 alloc/4160 real, 128)
    bf16* suaTb  = (bf16*)takeB(524288);   // (2048, 128)
    // NS bf16 (each 3x128x128)
    bf16* Sb16  = (bf16*)takeB(98304);
    bf16* Cb16  = (bf16*)takeB(98304);
    bf16* Mb16  = (bf16*)takeB(98304);
    bf16* MTb16 = (bf16*)takeB(98304);
    bf16* Fb16  = (bf16*)takeB(98304);
    bf16* FTb16 = (bf16*)takeB(98304);
    bf16* FcAb  = (bf16*)takeB(98304);
    bf16* FcTAb = (bf16*)takeB(98304);
    bf16* FcBb  = (bf16*)takeB(98304);
    bf16* FcTBb = (bf16*)takeB(98304);
    bf16* Zb16  = (bf16*)takeB(98304);
    bf16* ZTb16 = (bf16*)takeB(98304);

    auto gemmB = [&](int outbf, int cinbf, const bf16* A, const bf16* Bt,
                     const void* Cin, void* C, int M, int N, int K, int ldc,
                     float alpha, float beta, int act, const float* sptr) {
        dim3 grid((N + 127) / 128, M / 128);
        if (outbf && cinbf) gemm_bt<1, 1><<<grid, 256, 0, stream>>>(A, Bt, Cin, C, M, N, K, ldc, alpha, beta, act, sptr);
        else if (outbf)     gemm_bt<1, 0><<<grid, 256, 0, stream>>>(A, Bt, Cin, C, M, N, K, ldc, alpha, beta, act, sptr);
        else                gemm_bt<0, 0><<<grid, 256, 0, stream>>>(A, Bt, Cin, C, M, N, K, ldc, alpha, beta, act, sptr);
    };
    auto gdir = [&](int outbf, int cinbf, const bf16* A, const bf16* Bt,
                    const void* Cin, void* C, int M, int N, int K, int ldc,
                    float alpha, float beta, int act, const float* sptr) {
        dim3 grid((N + 127) / 128, (M + 127) / 128);
        if (outbf && cinbf)      gemm_direct<1, 1><<<grid, 256, 0, stream>>>(A, Bt, Cin, C, M, N, K, ldc, alpha, beta, act, sptr);
        else if (outbf)          gemm_direct<1, 0><<<grid, 256, 0, stream>>>(A, Bt, Cin, C, M, N, K, ldc, alpha, beta, act, sptr);
        else if (cinbf)          gemm_direct<0, 1><<<grid, 256, 0, stream>>>(A, Bt, Cin, C, M, N, K, ldc, alpha, beta, act, sptr);
        else                     gemm_direct<0, 0><<<grid, 256, 0, stream>>>(A, Bt, Cin, C, M, N, K, ldc, alpha, beta, act, sptr);
    };
    // split-K: partials into partA (slabA), reduce into fp32 out
    auto skp = [&](const bf16* A, const bf16* Bt, float* out,
                   int M, int N, int K, int KC) {
        int SK = (K + KC - 1) / KC;
        gemm_skp<<<dim3((N + 127) / 128, (M + 127) / 128, SK), 256, 0, stream>>>(A, Bt, partA, M, N, K, KC);
        int MN = M * N;
        skred<<<(MN + 255) / 256, 256, 0, stream>>>(partA, out, SK, MN);
    };
    auto tconv = [&](const float* W, bf16* Wt, int K, int N, int Kpad) {
        tconv_kernel<<<dim3((Kpad + 31) / 32, (N + 31) / 32), 256, 0, stream>>>(W, Wt, K, N, Kpad);
    };

    // 0. weight converts
    tconv(qkvw, qkvwT, Dc, 3 * Dc, Dc);
    tconv(gw1, gw1T, Dc, GGH, Dc);
    tconv(wow, wowT, Dc, Dc, Dc);
    tconv(mw1, mw1T, FPOLY, MHID, FPOLY);
    tconv(mw2, mw2T, MHID, Dc, MHID);
    tconv(fw1, fw1T, Dc, FFNH, Dc);
    tconv(fw3, fw3T, Dc, FFNH, Dc);
    tconv(fw2, fw2T, FFNH, Dc, FFNHP);
    tconv(mwk, mwkTb, Dc, HDc, Dc);
    cvt_kernel<<<2048, 256, 0, stream>>>(mw2, mw2b, MHID * Dc);
    sgate_kernel<<<1, 1, 0, stream>>>(mgate, scal + 2);

    // 1-2. rmsnorm, q/k/v, gamma  (gg1 via split-K before vt occupies slabA)
    rms_rows<<<NTOK, 256, 0, stream>>>(x, n1w, hb, Dc);
    gemmB(1, 0, hb, qkvwT,          nullptr, qtb, NTOK, Dc, Dc, Dc, 1.f, 0.f, 0, nullptr);
    snr_one<<<dim3(Sc / 4, Hc, Bc), 256, 0, stream>>>(qtb, qnw, qnb);
    gemmB(1, 0, hb, qkvwT + (size_t)1024 * Dc, nullptr, qtb, NTOK, Dc, Dc, Dc, 1.f, 0.f, 0, nullptr);
    snr_one<<<dim3(Sc / 4, Hc, Bc), 256, 0, stream>>>(qtb, knw, knb);
    gemmB(1, 0, hb, qkvwT + (size_t)2048 * Dc, nullptr, vb, NTOK, Dc, Dc, Dc, 1.f, 0.f, 0, nullptr);
    skp(hb, gw1T, gg1, NTOK, GGH, Dc, 256);        // SK=4, 128 blocks
    gamma_kernel<<<NTOK / 4, 256, 0, stream>>>(gg1, gw2, gamma);
    cvt_kernel<<<2048, 256, 0, stream>>>(mw1, mw1b, FPOLY * MHID);   // hb dead

    // 3. V transpose, q_mem, attention
    vtrans_kernel<<<dim3(Sc / 32, 2, Bc * Hc), 256, 0, stream>>>(vb, vt);
    kpsum_kernel<<<dim3(Bc * Hc, 16), 64, 0, stream>>>(knb, psum);
    qmem2_kernel<<<dim3(Bc * Hc, 16), 64, 0, stream>>>(qnb, knb, gamma, psum, qmem);
    attn_mfma<<<dim3(Sc / 128, Hc, Bc), 256, 0, stream>>>(qnb, knb, vt, attnb);

    // 4. actives (vt dead -> slabA reusable as partials)
    gather_active<<<NACT, 256, 0, stream>>>(qmem, vb, xa, xab, va);
    wvec_kernel<<<1, 128, 0, stream>>>(gamma, wvec, scal);

    // 5. gradient chain (128 active tokens) -- split-K MFMA
    skp(xab, mwkTb, za, NACT, HDc, Dc, 64);                         // SK=16
    phi2_f32<<<dim3((FPOLY + 255) / 256, NACT), 256, 0, stream>>>(za, featA, featAb);
    skp(featAb, mw1T, ua, NACT, MHID, FPOLY, 288);                  // SK=15, 240 blocks
    silu_kernel<<<(NACT * MHID + 255) / 256, 256, 0, stream>>>(ua, sua, suab, NACT * MHID);
    skp(suab, mw2T, preda, NACT, Dc, MHID, 128);                    // SK=16, 128 blocks
    dpred_kernel<<<(NACT * Dc + 255) / 256, 256, 0, stream>>>(preda, va, wvec, scal, dpreda, dpredab);
    skp(dpredab, mw2b, dsua, NACT, MHID, Dc, 128);                  // SK=8, 128 blocks
    dsilu_kernel<<<(NACT * MHID + 255) / 256, 256, 0, stream>>>(dsua, ua, dua, duab, NACT * MHID);
    skp(duab, mw1b, dfeata, NACT, FPOLY, MHID, 256);                // SK=8, 264 blocks
    dz_kernel<<<NACT, 64, 0, stream>>>(dfeata, za, dza, dzab);

    // transposed bf16 copies for the NS/PT/weight-update path
    tconv(dua, duaTb, 128, MHID, 128);
    tconv(dpreda, dpredaTb, 128, Dc, 128);
    tconv(dza, dzaTb, 128, HDc, 128);
    tconv(xa, xaTb, 128, Dc, 128);
    tconv(featA, featATb, 128, FPOLY, 128);
    tconv(sua, suaTb, 128, MHID, 128);

    // 6. Newton-Schulz in 128x128 space (bf16 MFMA, batched z=3)
    gram_trick<<<1, 256, 0, stream>>>(za, SA);                      // S1 = poly-kernel of za
    skp(suab, suab, SA + 16384, 128, 128, MHID, 64);                // SK=32
    skp(xab, xab, SA + 32768, 128, 128, Dc, 64);                    // SK=16
    skp(duab, duab, CA, 128, 128, MHID, 64);
    skp(dpredab, dpredab, CA + 16384, 128, 128, Dc, 64);
    gdir(0, 0, dzab, dzab, nullptr, CA + 32768, 128, 128, HDc, 128, 1.f, 0.f, 0, nullptr);
    ns_norm_kernel<<<3, 256, 0, stream>>>(SA, CA, Sb16, Cb16, scal + 8);
    {
        bf16 *fc = FcAb, *fct = FcTAb, *fcn = FcBb, *fctn = FcTBb;
        for (int t = 0; t < 5; ++t) {
            bmm128<1><<<3, 256, 0, stream>>>(Sb16, Cb16, nullptr, Mb16, MTb16, 1.f, 0.f, 0.f);
            bmm128<1><<<3, 256, 0, stream>>>(Mb16, MTb16, Mb16, Fb16, FTb16, 2.0315f, -4.775f, 3.4445f);
            if (t == 0) copy3_kernel<<<192, 256, 0, stream>>>(Fb16, FTb16, FcAb, FcTAb);
            else {
                bmm128<1><<<3, 256, 0, stream>>>(fc, FTb16, nullptr, fcn, fctn, 1.f, 0.f, 0.f);
                bf16* t1 = fc; fc = fcn; fcn = t1;
                bf16* t2 = fct; fct = fctn; fctn = t2;
            }
            if (t < 4) {
                bmm128<1><<<3, 256, 0, stream>>>(Cb16, FTb16, nullptr, Zb16, ZTb16, 1.f, 0.f, 0.f);
                bmm128<0><<<3, 256, 0, stream>>>(ZTb16, FTb16, nullptr, Cb16, nullptr, 1.f, 0.f, 0.f);
            }
        }
        // P5 = PTraw^T @ Fc * invn
        gdir(1, 0, duaTb,    fct,         nullptr, PT1Tb, MHID, 128, 128, 128, 1.f, 0.f, 0, scal + 8);
        gdir(1, 0, dpredaTb, fct + 16384, nullptr, PT2Tb, Dc,   128, 128, 128, 1.f, 0.f, 0, scal + 9);
        gdir(1, 0, dzaTb,    fct + 32768, nullptr, PT3Tb, HDc,  128, 128, 128, 1.f, 0.f, 0, scal + 10);
    }
    // wkuT = 0.999*mwkT - 0.01*PT3T@xa
    gdir(1, 1, PT3Tb, xaTb, mwkTb, wkuTb, HDc, Dc, 128, Dc, -0.01f, 0.999f, 0, nullptr);
    // materialize updated memory weights (transposed, bf16):
    //   w1uT = 0.999*mw1T - 0.01*PT1T@featA   (mw1b dead -> slabG reuse)
    gemmB(1, 1, PT1Tb, featATb, mw1T, w1uT, MHID, FPOLY, 128, FPOLY, -0.01f, 0.999f, 0, nullptr);
    //   w2uT = 0.999*mw2T - 0.01*PT2T@sua
    gemmB(1, 1, PT2Tb, suaTb, mw2T, w2uT, Dc, MHID, 128, MHID, -0.01f, 0.999f, 0, nullptr);

    // 7. x2 = x + attn@wo; zf = qmem@wku
    gemmB(0, 0, attnb, wowT, x, x2, NTOK, Dc, Dc, Dc, 1.f, 1.f, 0, nullptr);
    cvt_kernel<<<2048, 256, 0, stream>>>(qmem, qmemb, NTOK * Dc);
    gdir(0, 0, qmemb, wkuTb, nullptr, zf, NTOK, HDc, Dc, HDc, 1.f, 0.f, 0, nullptr);

    // 8. memory forward with materialized updated weights, 2 chunks
    for (int c = 0; c < NTOK / MCH; ++c) {
        const int R = c * MCH;
        phi2_bf16<<<dim3((FPOLY + 255) / 256, MCH), 256, 0, stream>>>(zf + (size_t)R * HDc, featC);
        gemmB(1, 0, featC, w1uT, nullptr, t1b, MCH, MHID, FPOLY, MHID, 1.f, 0.f, 1, nullptr);
        gemmB(0, 0, t1b, w2uT, x2 + (size_t)R * Dc, x2 + (size_t)R * Dc,
              MCH, Dc, MHID, Dc, 1.f, 1.f, 0, scal + 2);
    }
    // 9. FFN (swiglu)
    rms_rows<<<NTOK, 256, 0, stream>>>(x2, n2w, h2b, Dc);
    gemmB(1, 0, h2b, fw1T, nullptr, ff1b, NTOK, FFNH, Dc, FFNHP, 1.f, 0.f, 1, nullptr);
    gemmB(1, 0, h2b, fw3T, nullptr, ff3b, NTOK, FFNH, Dc, FFNHP, 1.f, 0.f, 0, nullptr);
    mulpad_kernel<<<(NTOK * FFNHP + 255) / 256, 256, 0, stream>>>(ff1b, ff3b);
    gemmB(0, 0, ff1b, fw2T, x2, outp, NTOK, Dc, FFNHP, Dc, 1.f, 1.f, 0, nullptr);
}